// Round 5
// baseline (184.709 us; speedup 1.0000x reference)
//
#include <hip/hip_runtime.h>
#include <math.h>

typedef _Float16 hv8 __attribute__((ext_vector_type(8)));
typedef _Float16 hv4 __attribute__((ext_vector_type(4)));
typedef _Float16 hv2 __attribute__((ext_vector_type(2)));
typedef float f32x4 __attribute__((ext_vector_type(4)));

#define LDS_AS(p) ((__attribute__((address_space(3))) void*)(p))
#define GLB_AS(p) ((const __attribute__((address_space(1))) void*)(p))

// ---------------- fp32 -> fp16 convert (x) ----------------
__global__ void cvt_kernel(const float* __restrict__ in, _Float16* __restrict__ out, int n) {
  int i = (blockIdx.x * blockDim.x + threadIdx.x) * 4;
  const int stride = gridDim.x * blockDim.x * 4;
  for (; i < n; i += stride) {
    const float4 v = *reinterpret_cast<const float4*>(in + i);
    hv4 o = {(_Float16)v.x, (_Float16)v.y, (_Float16)v.z, (_Float16)v.w};
    *reinterpret_cast<hv4*>(out + i) = o;
  }
}

// ---------------- fp32 -> fp16 convert, all 4 weights in one launch ----------------
__global__ void cvt_w_kernel(const float* __restrict__ wq, const float* __restrict__ wk,
                             const float* __restrict__ wv, const float* __restrict__ wo,
                             _Float16* __restrict__ wqkv, _Float16* __restrict__ wob) {
  const int i = (blockIdx.x * blockDim.x + threadIdx.x) * 4;  // 0 .. 4M-4
  const int seg = i >> 20;  // uniform per block (1M-elem segments)
  const int r = i & 1048575;
  const float* s = (seg == 0) ? wq : (seg == 1) ? wk : (seg == 2) ? wv : wo;
  _Float16* d = (seg < 3) ? (wqkv + (size_t)seg * 1048576) : wob;
  const float4 v = *reinterpret_cast<const float4*>(s + r);
  hv4 o = {(_Float16)v.x, (_Float16)v.y, (_Float16)v.z, (_Float16)v.w};
  *reinterpret_cast<hv4*>(d + r) = o;
}

// ---------------- RoPE in-place on fused QKV [4096][3072]; Q|K = cols 0..2047 ----------------
__global__ void rope_kernel(_Float16* __restrict__ T) {
  const int idx = blockIdx.x * blockDim.x + threadIdx.x;
  const int pair = idx & 1023;  // hh*32 + i
  const int row = idx >> 10;    // b*2048 + pos
  const int pos = row & 2047;
  const int hh = pair >> 5, i = pair & 31;
  const float freq = exp2f((float)i * (-13.287712379549449f / 32.0f));
  const float ang = (float)pos * freq;
  float s, c;
  sincosf(ang, &s, &c);
  const size_t off = (size_t)row * 3072 + hh * 64 + 2 * i;
  hv2 v = *reinterpret_cast<const hv2*>(T + off);
  const float e = (float)v[0];
  const float o = (float)v[1];
  v[0] = (_Float16)(e * c - o * s);
  v[1] = (_Float16)(e * s + o * c);
  *reinterpret_cast<hv2*>(T + off) = v;
}

// ---------------- V transpose with pi-permuted kv storage ----------------
// Vt[bh][d][kvblk*64 + s] where slot s holds kv = kvblk*64 + (s>>5)*32 + ((s>>2)&1... )
// Precisely: for kv = ks*32 + hi*16 + g*4 + lo  ->  s = ks*32 + g*8 + hi*4 + lo.
// This makes attn's PV A-fragment (slots ks*32+g*8 .. +7) a single contiguous b128 read.
__global__ __launch_bounds__(256) void vtrans_kernel(const _Float16* __restrict__ QKV,
                                                     _Float16* __restrict__ Vt) {
  __shared__ __align__(16) _Float16 Ts[64][72];
  const int t = threadIdx.x;
  const int n0 = blockIdx.x * 64;
  const int bh = blockIdx.y;
  const int b = bh >> 4, h = bh & 15;
  const _Float16* src = QKV + (size_t)(b * 2048 + n0) * 3072 + 2048 + h * 64;
#pragma unroll
  for (int i = 0; i < 2; i++) {
    const int s = i * 256 + t, r = s >> 3, c = (s & 7) * 8;
    *reinterpret_cast<hv8*>(&Ts[r][c]) = *reinterpret_cast<const hv8*>(src + (size_t)r * 3072 + c);
  }
  __syncthreads();
  _Float16* dst = Vt + (size_t)bh * 64 * 2048 + n0;
#pragma unroll
  for (int i = 0; i < 2; i++) {
    const int s = i * 256 + t, c = s >> 3, r0 = (s & 7) * 8;  // kv rows r0..r0+7, col d=c
    // sigma_inv(r0) for the low 4-element run; +8 for the r0+4 run
    const int base0 = (r0 & 32) + ((r0 & 8) ? 16 : 0) + ((r0 & 16) ? 4 : 0);
    hv4 o0, o1;
#pragma unroll
    for (int k = 0; k < 4; k++) { o0[k] = Ts[r0 + k][c]; o1[k] = Ts[r0 + 4 + k][c]; }
    *reinterpret_cast<hv4*>(dst + (size_t)c * 2048 + base0) = o0;
    *reinterpret_cast<hv4*>(dst + (size_t)c * 2048 + base0 + 8) = o1;
  }
}

// ---------------- NT GEMM: C[m][n] = sum_k A[m][k] * B[n][k] ---------------- (unchanged)
template <int BM, typename OutT>
__global__ __launch_bounds__(256) void gemm_nt(const _Float16* __restrict__ A,
                                               const _Float16* __restrict__ B,
                                               OutT* __restrict__ C,
                                               const int M, const int N, const int K) {
  constexpr int MI = BM / 32;
  constexpr int ALOADS = BM / 64;
  __shared__ __align__(16) _Float16 As[BM * 32];
  __shared__ __align__(16) _Float16 Bs[128 * 32];
  const int t = threadIdx.x;
  const int w = t >> 6, lane = t & 63;
  const int wr = w >> 1, wc = w & 1;
  const int g = lane >> 4, lr = lane & 15;
  const int mBase = blockIdx.y * BM, nBase = blockIdx.x * 128;

  f32x4 acc[MI][4];
#pragma unroll
  for (int a = 0; a < MI; a++)
#pragma unroll
    for (int bb = 0; bb < 4; bb++) acc[a][bb] = {0.f, 0.f, 0.f, 0.f};

  const int srow = t >> 2;
  const int scol = (t & 3) * 8;
  for (int k0 = 0; k0 < K; k0 += 32) {
#pragma unroll
    for (int i = 0; i < ALOADS; i++) {
      const _Float16* ga = A + (size_t)(mBase + i * 64 + srow) * K + k0 + scol;
      __builtin_amdgcn_global_load_lds(GLB_AS(ga), LDS_AS(As + (i * 256 + w * 64) * 8), 16, 0, 0);
    }
#pragma unroll
    for (int i = 0; i < 2; i++) {
      const _Float16* gb = B + (size_t)(nBase + i * 64 + srow) * K + k0 + scol;
      __builtin_amdgcn_global_load_lds(GLB_AS(gb), LDS_AS(Bs + (i * 256 + w * 64) * 8), 16, 0, 0);
    }
    __syncthreads();
    hv8 af[MI], bfr[4];
#pragma unroll
    for (int mi = 0; mi < MI; mi++)
      af[mi] = *reinterpret_cast<const hv8*>(As + (wr * (BM / 2) + mi * 16 + lr) * 32 + g * 8);
#pragma unroll
    for (int ni = 0; ni < 4; ni++)
      bfr[ni] = *reinterpret_cast<const hv8*>(Bs + (wc * 64 + ni * 16 + lr) * 32 + g * 8);
#pragma unroll
    for (int mi = 0; mi < MI; mi++)
#pragma unroll
      for (int ni = 0; ni < 4; ni++)
        acc[mi][ni] = __builtin_amdgcn_mfma_f32_16x16x32_f16(af[mi], bfr[ni], acc[mi][ni], 0, 0, 0);
    __syncthreads();
  }
#pragma unroll
  for (int mi = 0; mi < MI; mi++) {
#pragma unroll
    for (int j = 0; j < 4; j++) {
      const size_t row = mBase + wr * (BM / 2) + mi * 16 + g * 4 + j;
#pragma unroll
      for (int ni = 0; ni < 4; ni++) {
        const int col = nBase + wc * 64 + ni * 16 + lr;
        C[row * N + col] = (OutT)acc[mi][ni][j];
      }
    }
  }
}

// ---------------- flash causal attention, 2-wave blocks, in-register softmax ----------------
// Block = 32 q-rows (2 waves x 16), KV tiles of 64, heavy-first. Swapped QK^T (S^T = K Q^T):
// lane's 16 S-values all belong to q = m0 + w*16 + (lane&15). Softmax in exp2 domain
// (log2e folded into Q scale). PV via pi-permuted Vt storage -> A-frag = one b128 read.
__global__ __launch_bounds__(128) void attn_kernel(const _Float16* __restrict__ QKV,
                                                   const _Float16* __restrict__ Vt,
                                                   _Float16* __restrict__ O) {
  __shared__ __align__(16) _Float16 Ks[64 * 64];
  __shared__ __align__(16) _Float16 Vs[64 * 64];
  const int t = threadIdx.x;
  const int w = t >> 6, lane = t & 63;
  const int g = lane >> 4, lr = lane & 15;
  const int qt = (int)(gridDim.x - 1 - blockIdx.x);  // heavy-first dispatch
  const int m0 = qt * 32;
  const int bh = blockIdx.y;
  const int b = bh >> 4, h = bh & 15;
  const _Float16* Qp = QKV + (size_t)b * 2048 * 3072 + h * 64;
  const _Float16* Kp = Qp + 1024;
  const _Float16* Vp = Vt + (size_t)bh * 64 * 2048;
  _Float16* Op = O + (size_t)b * 2048 * 1024 + h * 64;

  const int qg = m0 + w * 16 + lr;  // this lane's q row

  // Q B-frag (n=q, k=g*8+i), pre-scaled by (1/8)*log2(e) for exp2-domain softmax
  hv8 qf[2];
#pragma unroll
  for (int ks = 0; ks < 2; ks++) {
    qf[ks] = *reinterpret_cast<const hv8*>(Qp + (size_t)qg * 3072 + ks * 32 + g * 8);
    qf[ks] = qf[ks] * (_Float16)0.18033688f;
  }

  f32x4 oacc[4];  // O^T frags: row d = dblk*16+g*4+j, col q = qg (lane-local)
#pragma unroll
  for (int d = 0; d < 4; d++) oacc[d] = {0.f, 0.f, 0.f, 0.f};
  float mst = -INFINITY, lst = 0.f;

  for (int kv0 = 0; kv0 < m0 + 32; kv0 += 64) {
    // stage K tile [64 kv][64 d] and V tile [64 d][64 kv-permuted], XOR-swizzled source
#pragma unroll
    for (int i = 0; i < 4; i++) {
      const int s = i * 128 + t;
      const int r = s >> 3;
      const int cs = ((s & 7) ^ (r & 7)) * 8;
      __builtin_amdgcn_global_load_lds(GLB_AS(Kp + (size_t)(kv0 + r) * 3072 + cs),
                                       LDS_AS(Ks + s * 8), 16, 0, 0);
      __builtin_amdgcn_global_load_lds(GLB_AS(Vp + (size_t)r * 2048 + kv0 + cs),
                                       LDS_AS(Vs + s * 8), 16, 0, 0);
    }
    __syncthreads();

    // S^T = K Q^T : A = K rows (m=kv), B = Q (n=q). 4 kv-frags x 2 k-steps.
    f32x4 sf[4];
#pragma unroll
    for (int nf = 0; nf < 4; nf++) sf[nf] = {0.f, 0.f, 0.f, 0.f};
#pragma unroll
    for (int ks = 0; ks < 2; ks++)
#pragma unroll
      for (int nf = 0; nf < 4; nf++) {
        const hv8 kf = *reinterpret_cast<const hv8*>(
            Ks + (nf * 16 + lr) * 64 + (((ks * 4 + g) ^ (lr & 7)) * 8));
        sf[nf] = __builtin_amdgcn_mfma_f32_16x16x32_f16(kf, qf[ks], sf[nf], 0, 0, 0);
      }

    // lane (g,lr): sf[nf][j] = S2[q=qg][kv = kv0 + nf*16 + g*4 + j]  (log2 domain)
    const bool diag = (kv0 + 63 > m0 + w * 16);
    float v[4][4];
#pragma unroll
    for (int nf = 0; nf < 4; nf++)
#pragma unroll
      for (int j = 0; j < 4; j++) {
        float x = sf[nf][j];
        if (diag && (kv0 + nf * 16 + g * 4 + j > qg)) x = -INFINITY;
        v[nf][j] = x;
      }

    // online softmax (base-2): in-lane reduce over 16, cross-g via 2 shfls
    float rm = v[0][0];
#pragma unroll
    for (int nf = 0; nf < 4; nf++)
#pragma unroll
      for (int j = 0; j < 4; j++) rm = fmaxf(rm, v[nf][j]);
    rm = fmaxf(rm, __shfl_xor(rm, 16));
    rm = fmaxf(rm, __shfl_xor(rm, 32));
    const float mn = fmaxf(mst, rm);
    const float corr = exp2f(mst - mn);  // first tile: exp2(-inf)=0
    float p[4][4];
    float rs = 0.f;
#pragma unroll
    for (int nf = 0; nf < 4; nf++)
#pragma unroll
      for (int j = 0; j < 4; j++) {
        p[nf][j] = exp2f(v[nf][j] - mn);
        rs += p[nf][j];
      }
    rs += __shfl_xor(rs, 16);
    rs += __shfl_xor(rs, 32);
    lst = lst * corr + rs;
    mst = mn;
#pragma unroll
    for (int d = 0; d < 4; d++) oacc[d] *= corr;

    // P^T B-frags, lane-local: pf[ks][i] = P[qg][kv0 + ks*32 + (i>>2)*16 + g*4 + (i&3)]
    hv8 pf[2];
#pragma unroll
    for (int ks = 0; ks < 2; ks++)
#pragma unroll
      for (int i = 0; i < 8; i++) pf[ks][i] = (_Float16)p[ks * 2 + (i >> 2)][i & 3];

    // O^T += V^T P^T : A-frag = Vs row d, slots ks*32+g*8..+7 = one b128 swizzled read
#pragma unroll
    for (int dblk = 0; dblk < 4; dblk++) {
      const int row = dblk * 16 + lr;
#pragma unroll
      for (int ks = 0; ks < 2; ks++) {
        const hv8 vtf = *reinterpret_cast<const hv8*>(
            Vs + row * 64 + (((ks * 4 + g) ^ (row & 7)) * 8));
        oacc[dblk] = __builtin_amdgcn_mfma_f32_16x16x32_f16(vtf, pf[ks], oacc[dblk], 0, 0, 0);
      }
    }
    __syncthreads();  // protect Ks/Vs for next tile's staging
  }

  // epilogue: oacc[dblk][j] = O^T[d=dblk*16+g*4+j][qg] -> 4x 8B stores
  const float inv = 1.0f / lst;
#pragma unroll
  for (int dblk = 0; dblk < 4; dblk++) {
    hv4 o;
#pragma unroll
    for (int j = 0; j < 4; j++) o[j] = (_Float16)(oacc[dblk][j] * inv);
    *reinterpret_cast<hv4*>(Op + (size_t)qg * 1024 + dblk * 16 + g * 4) = o;
  }
}

extern "C" void kernel_launch(void* const* d_in, const int* in_sizes, int n_in,
                              void* d_out, int out_size, void* d_ws, size_t ws_size,
                              hipStream_t stream) {
  const float* x = (const float*)d_in[0];
  const float* wq = (const float*)d_in[1];
  const float* wk = (const float*)d_in[2];
  const float* wv = (const float*)d_in[3];
  const float* wo = (const float*)d_in[4];
  float* out = (float*)d_out;
  char* ws = (char*)d_ws;
  const size_t MB = 1ull << 20;
  _Float16* xb   = (_Float16*)(ws + 0 * MB);   // 8 MB (A operand for QKV gemm)
  _Float16* wqkv = (_Float16*)(ws + 8 * MB);   // 6 MB (wq|wk|wv contiguous rows)
  _Float16* wob  = (_Float16*)(ws + 14 * MB);  // 2 MB
  _Float16* QKV  = (_Float16*)(ws + 16 * MB);  // 24 MB [4096][3072]
  _Float16* Vtb  = (_Float16*)(ws + 40 * MB);  // 8 MB  [32][64][2048] pi-permuted
  _Float16* Ab   = (_Float16*)(ws + 0 * MB);   // 8 MB  (reuses xb after QKV gemm)

  cvt_kernel<<<2048, 256, 0, stream>>>(x, xb, 4194304);
  cvt_w_kernel<<<4096, 256, 0, stream>>>(wq, wk, wv, wo, wqkv, wob);

  // fused Q|K|V projection: [4096][3072]
  gemm_nt<128, _Float16><<<dim3(24, 32), 256, 0, stream>>>(xb, wqkv, QKV, 4096, 3072, 1024);

  rope_kernel<<<16384, 256, 0, stream>>>(QKV);
  vtrans_kernel<<<dim3(32, 32), 256, 0, stream>>>(QKV, Vtb);

  attn_kernel<<<dim3(64, 32), 128, 0, stream>>>(QKV, Vtb, Ab);

  gemm_nt<64, float><<<dim3(8, 64), 256, 0, stream>>>(Ab, wob, out, 4096, 1024, 1024);
}

// Round 7
// 165.037 us; speedup vs baseline: 1.1192x; 1.1192x over previous
//
#include <hip/hip_runtime.h>
#include <math.h>

typedef _Float16 hv8 __attribute__((ext_vector_type(8)));
typedef _Float16 hv4 __attribute__((ext_vector_type(4)));
typedef _Float16 hv2 __attribute__((ext_vector_type(2)));
typedef float f32x4 __attribute__((ext_vector_type(4)));

#define LDS_AS(p) ((__attribute__((address_space(3))) void*)(p))
#define GLB_AS(p) ((const __attribute__((address_space(1))) void*)(p))

// ---------------- fp32 -> fp16 convert (x) ----------------
__global__ void cvt_kernel(const float* __restrict__ in, _Float16* __restrict__ out, int n) {
  int i = (blockIdx.x * blockDim.x + threadIdx.x) * 4;
  const int stride = gridDim.x * blockDim.x * 4;
  for (; i < n; i += stride) {
    const float4 v = *reinterpret_cast<const float4*>(in + i);
    hv4 o = {(_Float16)v.x, (_Float16)v.y, (_Float16)v.z, (_Float16)v.w};
    *reinterpret_cast<hv4*>(out + i) = o;
  }
}

// ---------------- fp32 -> fp16 convert, all 4 weights in one launch ----------------
__global__ void cvt_w_kernel(const float* __restrict__ wq, const float* __restrict__ wk,
                             const float* __restrict__ wv, const float* __restrict__ wo,
                             _Float16* __restrict__ wqkv, _Float16* __restrict__ wob) {
  const int i = (blockIdx.x * blockDim.x + threadIdx.x) * 4;  // 0 .. 4M-4
  const int seg = i >> 20;  // uniform per block (1M-elem segments)
  const int r = i & 1048575;
  const float* s = (seg == 0) ? wq : (seg == 1) ? wk : (seg == 2) ? wv : wo;
  _Float16* d = (seg < 3) ? (wqkv + (size_t)seg * 1048576) : wob;
  const float4 v = *reinterpret_cast<const float4*>(s + r);
  hv4 o = {(_Float16)v.x, (_Float16)v.y, (_Float16)v.z, (_Float16)v.w};
  *reinterpret_cast<hv4*>(d + r) = o;
}

// ---------------- RoPE in-place on fused QKV [4096][3072]; Q|K = cols 0..2047 ----------------
__global__ void rope_kernel(_Float16* __restrict__ T) {
  const int idx = blockIdx.x * blockDim.x + threadIdx.x;
  const int pair = idx & 1023;  // hh*32 + i
  const int row = idx >> 10;    // b*2048 + pos
  const int pos = row & 2047;
  const int hh = pair >> 5, i = pair & 31;
  const float freq = exp2f((float)i * (-13.287712379549449f / 32.0f));
  const float ang = (float)pos * freq;
  float s, c;
  sincosf(ang, &s, &c);
  const size_t off = (size_t)row * 3072 + hh * 64 + 2 * i;
  hv2 v = *reinterpret_cast<const hv2*>(T + off);
  const float e = (float)v[0];
  const float o = (float)v[1];
  v[0] = (_Float16)(e * c - o * s);
  v[1] = (_Float16)(e * s + o * c);
  *reinterpret_cast<hv2*>(T + off) = v;
}

// ---------------- V transpose with pi-permuted kv storage ----------------
// For kv = ks*32 + hi*16 + g*4 + lo  ->  slot s = ks*32 + g*8 + hi*4 + lo (within 64-block).
// Makes attn's PV A-fragment a single contiguous b128 read (verified: 0 bank conflicts in R5).
__global__ __launch_bounds__(256) void vtrans_kernel(const _Float16* __restrict__ QKV,
                                                     _Float16* __restrict__ Vt) {
  __shared__ __align__(16) _Float16 Ts[64][72];
  const int t = threadIdx.x;
  const int n0 = blockIdx.x * 64;
  const int bh = blockIdx.y;
  const int b = bh >> 4, h = bh & 15;
  const _Float16* src = QKV + (size_t)(b * 2048 + n0) * 3072 + 2048 + h * 64;
#pragma unroll
  for (int i = 0; i < 2; i++) {
    const int s = i * 256 + t, r = s >> 3, c = (s & 7) * 8;
    *reinterpret_cast<hv8*>(&Ts[r][c]) = *reinterpret_cast<const hv8*>(src + (size_t)r * 3072 + c);
  }
  __syncthreads();
  _Float16* dst = Vt + (size_t)bh * 64 * 2048 + n0;
#pragma unroll
  for (int i = 0; i < 2; i++) {
    const int s = i * 256 + t, c = s >> 3, r0 = (s & 7) * 8;  // kv rows r0..r0+7, col d=c
    const int base0 = (r0 & 32) + ((r0 & 8) ? 16 : 0) + ((r0 & 16) ? 4 : 0);
    hv4 o0, o1;
#pragma unroll
    for (int k = 0; k < 4; k++) { o0[k] = Ts[r0 + k][c]; o1[k] = Ts[r0 + 4 + k][c]; }
    *reinterpret_cast<hv4*>(dst + (size_t)c * 2048 + base0) = o0;
    *reinterpret_cast<hv4*>(dst + (size_t)c * 2048 + base0 + 8) = o1;
  }
}

// ---------------- NT GEMM: C[m][n] = sum_k A[m][k] * B[n][k] ---------------- (unchanged)
template <int BM, typename OutT>
__global__ __launch_bounds__(256) void gemm_nt(const _Float16* __restrict__ A,
                                               const _Float16* __restrict__ B,
                                               OutT* __restrict__ C,
                                               const int M, const int N, const int K) {
  constexpr int MI = BM / 32;
  constexpr int ALOADS = BM / 64;
  __shared__ __align__(16) _Float16 As[BM * 32];
  __shared__ __align__(16) _Float16 Bs[128 * 32];
  const int t = threadIdx.x;
  const int w = t >> 6, lane = t & 63;
  const int wr = w >> 1, wc = w & 1;
  const int g = lane >> 4, lr = lane & 15;
  const int mBase = blockIdx.y * BM, nBase = blockIdx.x * 128;

  f32x4 acc[MI][4];
#pragma unroll
  for (int a = 0; a < MI; a++)
#pragma unroll
    for (int bb = 0; bb < 4; bb++) acc[a][bb] = {0.f, 0.f, 0.f, 0.f};

  const int srow = t >> 2;
  const int scol = (t & 3) * 8;
  for (int k0 = 0; k0 < K; k0 += 32) {
#pragma unroll
    for (int i = 0; i < ALOADS; i++) {
      const _Float16* ga = A + (size_t)(mBase + i * 64 + srow) * K + k0 + scol;
      __builtin_amdgcn_global_load_lds(GLB_AS(ga), LDS_AS(As + (i * 256 + w * 64) * 8), 16, 0, 0);
    }
#pragma unroll
    for (int i = 0; i < 2; i++) {
      const _Float16* gb = B + (size_t)(nBase + i * 64 + srow) * K + k0 + scol;
      __builtin_amdgcn_global_load_lds(GLB_AS(gb), LDS_AS(Bs + (i * 256 + w * 64) * 8), 16, 0, 0);
    }
    __syncthreads();
    hv8 af[MI], bfr[4];
#pragma unroll
    for (int mi = 0; mi < MI; mi++)
      af[mi] = *reinterpret_cast<const hv8*>(As + (wr * (BM / 2) + mi * 16 + lr) * 32 + g * 8);
#pragma unroll
    for (int ni = 0; ni < 4; ni++)
      bfr[ni] = *reinterpret_cast<const hv8*>(Bs + (wc * 64 + ni * 16 + lr) * 32 + g * 8);
#pragma unroll
    for (int mi = 0; mi < MI; mi++)
#pragma unroll
      for (int ni = 0; ni < 4; ni++)
        acc[mi][ni] = __builtin_amdgcn_mfma_f32_16x16x32_f16(af[mi], bfr[ni], acc[mi][ni], 0, 0, 0);
    __syncthreads();
  }
#pragma unroll
  for (int mi = 0; mi < MI; mi++) {
#pragma unroll
    for (int j = 0; j < 4; j++) {
      const size_t row = mBase + wr * (BM / 2) + mi * 16 + g * 4 + j;
#pragma unroll
      for (int ni = 0; ni < 4; ni++) {
        const int col = nBase + wc * 64 + ni * 16 + lr;
        C[row * N + col] = (OutT)acc[mi][ni][j];
      }
    }
  }
}

// ---------------- flash causal attention ----------------
// 4 waves/block, QBLK=64 q-rows, KV tiles of 64, heavy-first, double-buffered K/V staging
// (STAGE(t+1) issued before compute(t); single __syncthreads per tile whose implicit
// vmcnt(0) lands after a full compute phase). Swapped QK^T (S^T = K Q^T): lane's 16
// S-values all belong to q = m0 + w*16 + (lane&15). Softmax in exp2 domain, in-register,
// defer-max (skip rescale when max growth <= 8). PV via pi-permuted Vt -> b128 A-frag.
__global__ __launch_bounds__(256) void attn_kernel(const _Float16* __restrict__ QKV,
                                                   const _Float16* __restrict__ Vt,
                                                   _Float16* __restrict__ O) {
  __shared__ __align__(16) _Float16 Ks[2][64 * 64];
  __shared__ __align__(16) _Float16 Vs[2][64 * 64];
  const int t = threadIdx.x;
  const int w = t >> 6, lane = t & 63;
  const int g = lane >> 4, lr = lane & 15;
  const int m0 = (int)(gridDim.x - 1 - blockIdx.x) * 64;  // heavy-first dispatch
  const int bh = blockIdx.y;
  const int b = bh >> 4, h = bh & 15;
  const _Float16* Qp = QKV + (size_t)b * 2048 * 3072 + h * 64;
  const _Float16* Kp = Qp + 1024;
  const _Float16* Vp = Vt + (size_t)bh * 64 * 2048;
  _Float16* Op = O + (size_t)b * 2048 * 1024 + h * 64;

  const int qg = m0 + w * 16 + lr;  // this lane's q row

  // Q B-frag (n=q, k=g*8+i), pre-scaled by (1/8)*log2(e) for exp2-domain softmax
  hv8 qf[2];
#pragma unroll
  for (int ks = 0; ks < 2; ks++) {
    qf[ks] = *reinterpret_cast<const hv8*>(Qp + (size_t)qg * 3072 + ks * 32 + g * 8);
    qf[ks] = qf[ks] * (_Float16)0.18033688f;
  }

  // stage one 64x64 K tile + one 64x64 V tile into buffer `bi` (4 loads/thread)
  auto STAGE = [&](int kv0, int bi) {
#pragma unroll
    for (int i = 0; i < 2; i++) {
      const int s = i * 256 + t;
      const int r = s >> 3;
      const int cs = ((s & 7) ^ (r & 7)) * 8;
      __builtin_amdgcn_global_load_lds(GLB_AS(Kp + (size_t)(kv0 + r) * 3072 + cs),
                                       LDS_AS(&Ks[bi][s * 8]), 16, 0, 0);
      __builtin_amdgcn_global_load_lds(GLB_AS(Vp + (size_t)r * 2048 + kv0 + cs),
                                       LDS_AS(&Vs[bi][s * 8]), 16, 0, 0);
    }
  };

  f32x4 oacc[4];  // O^T frags: row d = dblk*16+g*4+j, col q = qg (lane-local)
#pragma unroll
  for (int d = 0; d < 4; d++) oacc[d] = {0.f, 0.f, 0.f, 0.f};
  float mst = -INFINITY, lst = 0.f;

  const int nt = m0 / 64 + 1;
  STAGE(0, 0);
  int cur = 0;

  for (int tt = 0; tt < nt; tt++) {
    // implicit vmcnt(0)+barrier: tile tt's staging (in flight for the whole previous
    // compute phase) is complete, and all waves are done reading buffer cur^1.
    __syncthreads();
    if (tt + 1 < nt) STAGE((tt + 1) * 64, cur ^ 1);
    const int kv0 = tt * 64;
    const _Float16* Kb = Ks[cur];
    const _Float16* Vb = Vs[cur];

    // S^T = K Q^T : A = K rows (m=kv), B = Q (n=q). 4 kv-frags x 2 k-steps.
    f32x4 sf[4];
#pragma unroll
    for (int nf = 0; nf < 4; nf++) sf[nf] = {0.f, 0.f, 0.f, 0.f};
#pragma unroll
    for (int ks = 0; ks < 2; ks++)
#pragma unroll
      for (int nf = 0; nf < 4; nf++) {
        const hv8 kf = *reinterpret_cast<const hv8*>(
            Kb + (nf * 16 + lr) * 64 + (((ks * 4 + g) ^ (lr & 7)) * 8));
        sf[nf] = __builtin_amdgcn_mfma_f32_16x16x32_f16(kf, qf[ks], sf[nf], 0, 0, 0);
      }

    // lane (g,lr): p[nf][j] = S2[q=qg][kv = kv0 + nf*16 + g*4 + j]  (log2 domain)
    const bool diag = (tt == nt - 1);
    float p[4][4];
#pragma unroll
    for (int nf = 0; nf < 4; nf++)
#pragma unroll
      for (int j = 0; j < 4; j++) {
        float x = sf[nf][j];
        if (diag && (kv0 + nf * 16 + g * 4 + j > qg)) x = -INFINITY;
        p[nf][j] = x;
      }

    // online softmax (base-2), defer-max: skip rescale unless max grew by > 8
    float rm = p[0][0];
#pragma unroll
    for (int nf = 0; nf < 4; nf++)
#pragma unroll
      for (int j = 0; j < 4; j++) rm = fmaxf(rm, p[nf][j]);
    rm = fmaxf(rm, __shfl_xor(rm, 16));
    rm = fmaxf(rm, __shfl_xor(rm, 32));
    if (!__all(rm <= mst + 8.0f)) {
      const float mn = fmaxf(mst, rm);
      const float corr = exp2f(mst - mn);  // first tile: exp2(-inf)=0
      lst *= corr;
#pragma unroll
      for (int d = 0; d < 4; d++) oacc[d] *= corr;
      mst = mn;
    }
    float rs = 0.f;
#pragma unroll
    for (int nf = 0; nf < 4; nf++)
#pragma unroll
      for (int j = 0; j < 4; j++) {
        p[nf][j] = exp2f(p[nf][j] - mst);
        rs += p[nf][j];
      }
    rs += __shfl_xor(rs, 16);
    rs += __shfl_xor(rs, 32);
    lst += rs;

    // P^T B-frags, lane-local (packed cvt): pf[ks][i] = P[qg][kv0+ks*32+(i>>2)*16+g*4+(i&3)]
    // cvt_pkrtz returns __fp16x2; element-assign into the _Float16 vector (identity cvt).
    hv8 pf[2];
#pragma unroll
    for (int ks = 0; ks < 2; ks++) {
      const auto c0 = __builtin_amdgcn_cvt_pkrtz(p[2 * ks][0], p[2 * ks][1]);
      const auto c1 = __builtin_amdgcn_cvt_pkrtz(p[2 * ks][2], p[2 * ks][3]);
      const auto c2 = __builtin_amdgcn_cvt_pkrtz(p[2 * ks + 1][0], p[2 * ks + 1][1]);
      const auto c3 = __builtin_amdgcn_cvt_pkrtz(p[2 * ks + 1][2], p[2 * ks + 1][3]);
      pf[ks][0] = (_Float16)c0[0]; pf[ks][1] = (_Float16)c0[1];
      pf[ks][2] = (_Float16)c1[0]; pf[ks][3] = (_Float16)c1[1];
      pf[ks][4] = (_Float16)c2[0]; pf[ks][5] = (_Float16)c2[1];
      pf[ks][6] = (_Float16)c3[0]; pf[ks][7] = (_Float16)c3[1];
    }

    // O^T += V^T P^T : A-frag = Vb row d, slots ks*32+g*8..+7 = one b128 swizzled read
#pragma unroll
    for (int dblk = 0; dblk < 4; dblk++) {
      const int row = dblk * 16 + lr;
#pragma unroll
      for (int ks = 0; ks < 2; ks++) {
        const hv8 vtf = *reinterpret_cast<const hv8*>(
            Vb + row * 64 + (((ks * 4 + g) ^ (row & 7)) * 8));
        oacc[dblk] = __builtin_amdgcn_mfma_f32_16x16x32_f16(vtf, pf[ks], oacc[dblk], 0, 0, 0);
      }
    }
    cur ^= 1;
  }

  // epilogue: oacc[dblk][j] = O^T[d=dblk*16+g*4+j][qg] -> 4x 8B stores
  const float inv = 1.0f / lst;
#pragma unroll
  for (int dblk = 0; dblk < 4; dblk++) {
    hv4 o;
#pragma unroll
    for (int j = 0; j < 4; j++) o[j] = (_Float16)(oacc[dblk][j] * inv);
    *reinterpret_cast<hv4*>(Op + (size_t)qg * 1024 + dblk * 16 + g * 4) = o;
  }
}

extern "C" void kernel_launch(void* const* d_in, const int* in_sizes, int n_in,
                              void* d_out, int out_size, void* d_ws, size_t ws_size,
                              hipStream_t stream) {
  const float* x = (const float*)d_in[0];
  const float* wq = (const float*)d_in[1];
  const float* wk = (const float*)d_in[2];
  const float* wv = (const float*)d_in[3];
  const float* wo = (const float*)d_in[4];
  float* out = (float*)d_out;
  char* ws = (char*)d_ws;
  const size_t MB = 1ull << 20;
  _Float16* xb   = (_Float16*)(ws + 0 * MB);   // 8 MB (A operand for QKV gemm)
  _Float16* wqkv = (_Float16*)(ws + 8 * MB);   // 6 MB (wq|wk|wv contiguous rows)
  _Float16* wob  = (_Float16*)(ws + 14 * MB);  // 2 MB
  _Float16* QKV  = (_Float16*)(ws + 16 * MB);  // 24 MB [4096][3072]
  _Float16* Vtb  = (_Float16*)(ws + 40 * MB);  // 8 MB  [32][64][2048] pi-permuted
  _Float16* Ab   = (_Float16*)(ws + 0 * MB);   // 8 MB  (reuses xb after QKV gemm)

  cvt_kernel<<<2048, 256, 0, stream>>>(x, xb, 4194304);
  cvt_w_kernel<<<4096, 256, 0, stream>>>(wq, wk, wv, wo, wqkv, wob);

  // fused Q|K|V projection: [4096][3072]
  gemm_nt<128, _Float16><<<dim3(24, 32), 256, 0, stream>>>(xb, wqkv, QKV, 4096, 3072, 1024);

  rope_kernel<<<16384, 256, 0, stream>>>(QKV);
  vtrans_kernel<<<dim3(32, 32), 256, 0, stream>>>(QKV, Vtb);

  attn_kernel<<<dim3(32, 32), 256, 0, stream>>>(QKV, Vtb, Ab);

  gemm_nt<64, float><<<dim3(8, 64), 256, 0, stream>>>(Ab, wob, out, 4096, 1024, 1024);
}

// Round 8
// 160.919 us; speedup vs baseline: 1.1478x; 1.0256x over previous
//
#include <hip/hip_runtime.h>
#include <math.h>

typedef _Float16 hv8 __attribute__((ext_vector_type(8)));
typedef _Float16 hv4 __attribute__((ext_vector_type(4)));
typedef _Float16 hv2 __attribute__((ext_vector_type(2)));
typedef float f32x4 __attribute__((ext_vector_type(4)));

#define LDS_AS(p) ((__attribute__((address_space(3))) void*)(p))
#define GLB_AS(p) ((const __attribute__((address_space(1))) void*)(p))

// ---------------- fp32 -> fp16 convert (x) ----------------
__global__ void cvt_kernel(const float* __restrict__ in, _Float16* __restrict__ out, int n) {
  int i = (blockIdx.x * blockDim.x + threadIdx.x) * 4;
  const int stride = gridDim.x * blockDim.x * 4;
  for (; i < n; i += stride) {
    const float4 v = *reinterpret_cast<const float4*>(in + i);
    hv4 o = {(_Float16)v.x, (_Float16)v.y, (_Float16)v.z, (_Float16)v.w};
    *reinterpret_cast<hv4*>(out + i) = o;
  }
}

// ---------------- fp32 -> fp16 convert, all 4 weights in one launch ----------------
__global__ void cvt_w_kernel(const float* __restrict__ wq, const float* __restrict__ wk,
                             const float* __restrict__ wv, const float* __restrict__ wo,
                             _Float16* __restrict__ wqkv, _Float16* __restrict__ wob) {
  const int i = (blockIdx.x * blockDim.x + threadIdx.x) * 4;  // 0 .. 4M-4
  const int seg = i >> 20;  // uniform per block (1M-elem segments)
  const int r = i & 1048575;
  const float* s = (seg == 0) ? wq : (seg == 1) ? wk : (seg == 2) ? wv : wo;
  _Float16* d = (seg < 3) ? (wqkv + (size_t)seg * 1048576) : wob;
  const float4 v = *reinterpret_cast<const float4*>(s + r);
  hv4 o = {(_Float16)v.x, (_Float16)v.y, (_Float16)v.z, (_Float16)v.w};
  *reinterpret_cast<hv4*>(d + r) = o;
}

// ---------------- RoPE in-place on fused QKV [4096][3072]; Q|K = cols 0..2047 ----------------
__global__ void rope_kernel(_Float16* __restrict__ T) {
  const int idx = blockIdx.x * blockDim.x + threadIdx.x;
  const int pair = idx & 1023;  // hh*32 + i
  const int row = idx >> 10;    // b*2048 + pos
  const int pos = row & 2047;
  const int hh = pair >> 5, i = pair & 31;
  const float freq = exp2f((float)i * (-13.287712379549449f / 32.0f));
  const float ang = (float)pos * freq;
  float s, c;
  sincosf(ang, &s, &c);
  const size_t off = (size_t)row * 3072 + hh * 64 + 2 * i;
  hv2 v = *reinterpret_cast<const hv2*>(T + off);
  const float e = (float)v[0];
  const float o = (float)v[1];
  v[0] = (_Float16)(e * c - o * s);
  v[1] = (_Float16)(e * s + o * c);
  *reinterpret_cast<hv2*>(T + off) = v;
}

// ---------------- V transpose with pi-permuted kv storage ----------------
// For kv = ks*32 + hi*16 + g*4 + lo  ->  slot s = ks*32 + g*8 + hi*4 + lo (within 64-block).
// Makes attn's PV A-fragment a single contiguous b128 read (verified: 0 bank conflicts).
__global__ __launch_bounds__(256) void vtrans_kernel(const _Float16* __restrict__ QKV,
                                                     _Float16* __restrict__ Vt) {
  __shared__ __align__(16) _Float16 Ts[64][72];
  const int t = threadIdx.x;
  const int n0 = blockIdx.x * 64;
  const int bh = blockIdx.y;
  const int b = bh >> 4, h = bh & 15;
  const _Float16* src = QKV + (size_t)(b * 2048 + n0) * 3072 + 2048 + h * 64;
#pragma unroll
  for (int i = 0; i < 2; i++) {
    const int s = i * 256 + t, r = s >> 3, c = (s & 7) * 8;
    *reinterpret_cast<hv8*>(&Ts[r][c]) = *reinterpret_cast<const hv8*>(src + (size_t)r * 3072 + c);
  }
  __syncthreads();
  _Float16* dst = Vt + (size_t)bh * 64 * 2048 + n0;
#pragma unroll
  for (int i = 0; i < 2; i++) {
    const int s = i * 256 + t, c = s >> 3, r0 = (s & 7) * 8;  // kv rows r0..r0+7, col d=c
    const int base0 = (r0 & 32) + ((r0 & 8) ? 16 : 0) + ((r0 & 16) ? 4 : 0);
    hv4 o0, o1;
#pragma unroll
    for (int k = 0; k < 4; k++) { o0[k] = Ts[r0 + k][c]; o1[k] = Ts[r0 + 4 + k][c]; }
    *reinterpret_cast<hv4*>(dst + (size_t)c * 2048 + base0) = o0;
    *reinterpret_cast<hv4*>(dst + (size_t)c * 2048 + base0 + 8) = o1;
  }
}

// ---------------- NT GEMM: C[m][n] = sum_k A[m][k] * B[n][k] ---------------- (unchanged)
template <int BM, typename OutT>
__global__ __launch_bounds__(256) void gemm_nt(const _Float16* __restrict__ A,
                                               const _Float16* __restrict__ B,
                                               OutT* __restrict__ C,
                                               const int M, const int N, const int K) {
  constexpr int MI = BM / 32;
  constexpr int ALOADS = BM / 64;
  __shared__ __align__(16) _Float16 As[BM * 32];
  __shared__ __align__(16) _Float16 Bs[128 * 32];
  const int t = threadIdx.x;
  const int w = t >> 6, lane = t & 63;
  const int wr = w >> 1, wc = w & 1;
  const int g = lane >> 4, lr = lane & 15;
  const int mBase = blockIdx.y * BM, nBase = blockIdx.x * 128;

  f32x4 acc[MI][4];
#pragma unroll
  for (int a = 0; a < MI; a++)
#pragma unroll
    for (int bb = 0; bb < 4; bb++) acc[a][bb] = {0.f, 0.f, 0.f, 0.f};

  const int srow = t >> 2;
  const int scol = (t & 3) * 8;
  for (int k0 = 0; k0 < K; k0 += 32) {
#pragma unroll
    for (int i = 0; i < ALOADS; i++) {
      const _Float16* ga = A + (size_t)(mBase + i * 64 + srow) * K + k0 + scol;
      __builtin_amdgcn_global_load_lds(GLB_AS(ga), LDS_AS(As + (i * 256 + w * 64) * 8), 16, 0, 0);
    }
#pragma unroll
    for (int i = 0; i < 2; i++) {
      const _Float16* gb = B + (size_t)(nBase + i * 64 + srow) * K + k0 + scol;
      __builtin_amdgcn_global_load_lds(GLB_AS(gb), LDS_AS(Bs + (i * 256 + w * 64) * 8), 16, 0, 0);
    }
    __syncthreads();
    hv8 af[MI], bfr[4];
#pragma unroll
    for (int mi = 0; mi < MI; mi++)
      af[mi] = *reinterpret_cast<const hv8*>(As + (wr * (BM / 2) + mi * 16 + lr) * 32 + g * 8);
#pragma unroll
    for (int ni = 0; ni < 4; ni++)
      bfr[ni] = *reinterpret_cast<const hv8*>(Bs + (wc * 64 + ni * 16 + lr) * 32 + g * 8);
#pragma unroll
    for (int mi = 0; mi < MI; mi++)
#pragma unroll
      for (int ni = 0; ni < 4; ni++)
        acc[mi][ni] = __builtin_amdgcn_mfma_f32_16x16x32_f16(af[mi], bfr[ni], acc[mi][ni], 0, 0, 0);
    __syncthreads();
  }
#pragma unroll
  for (int mi = 0; mi < MI; mi++) {
#pragma unroll
    for (int j = 0; j < 4; j++) {
      const size_t row = mBase + wr * (BM / 2) + mi * 16 + g * 4 + j;
#pragma unroll
      for (int ni = 0; ni < 4; ni++) {
        const int col = nBase + wc * 64 + ni * 16 + lr;
        C[row * N + col] = (OutT)acc[mi][ni][j];
      }
    }
  }
}

// ---------------- flash causal attention, fold-pair balanced ----------------
// Block x in [0,16) processes q-tiles qtA=x (light) and qtB=31-x (heavy) of one (b,h)
// in ONE shared KV sweep: every block = exactly 33 tile-computes -> perfect balance
// under any dispatch->CU mapping. During the shared prefix (kv tile <= qtA) each
// K/V fragment is loaded once and feeds both halves' MFMAs. Double-buffered staging,
// swapped QK^T (S^T = K Q^T), in-register exp2-domain softmax with defer-max,
// pi-permuted Vt -> b128 PV A-frags (0 bank conflicts, verified R5/R7).
__global__ __launch_bounds__(256) void attn_kernel(const _Float16* __restrict__ QKV,
                                                   const _Float16* __restrict__ Vt,
                                                   _Float16* __restrict__ O) {
  __shared__ __align__(16) _Float16 Ks[2][64 * 64];
  __shared__ __align__(16) _Float16 Vs[2][64 * 64];
  const int t = threadIdx.x;
  const int w = t >> 6, lane = t & 63;
  const int g = lane >> 4, lr = lane & 15;
  const int qtA = blockIdx.x;        // 0..15  (light q-tile)
  const int qtB = 31 - qtA;          // 16..31 (heavy q-tile)
  const int m0A = qtA * 64, m0B = qtB * 64;
  const int bh = blockIdx.y;
  const int b = bh >> 4, h = bh & 15;
  const _Float16* Qp = QKV + (size_t)b * 2048 * 3072 + h * 64;
  const _Float16* Kp = Qp + 1024;
  const _Float16* Vp = Vt + (size_t)bh * 64 * 2048;
  _Float16* Op = O + (size_t)b * 2048 * 1024 + h * 64;

  const int qgA = m0A + w * 16 + lr;
  const int qgB = m0B + w * 16 + lr;

  // Q B-frags (n=q, k=g*8+i), pre-scaled by (1/8)*log2(e) for exp2-domain softmax
  hv8 qfA[2], qfB[2];
#pragma unroll
  for (int ks = 0; ks < 2; ks++) {
    qfA[ks] = *reinterpret_cast<const hv8*>(Qp + (size_t)qgA * 3072 + ks * 32 + g * 8);
    qfA[ks] = qfA[ks] * (_Float16)0.18033688f;
    qfB[ks] = *reinterpret_cast<const hv8*>(Qp + (size_t)qgB * 3072 + ks * 32 + g * 8);
    qfB[ks] = qfB[ks] * (_Float16)0.18033688f;
  }

  auto STAGE = [&](int kv0, int bi) {
#pragma unroll
    for (int i = 0; i < 2; i++) {
      const int s = i * 256 + t;
      const int r = s >> 3;
      const int cs = ((s & 7) ^ (r & 7)) * 8;
      __builtin_amdgcn_global_load_lds(GLB_AS(Kp + (size_t)(kv0 + r) * 3072 + cs),
                                       LDS_AS(&Ks[bi][s * 8]), 16, 0, 0);
      __builtin_amdgcn_global_load_lds(GLB_AS(Vp + (size_t)r * 2048 + kv0 + cs),
                                       LDS_AS(&Vs[bi][s * 8]), 16, 0, 0);
    }
  };

  f32x4 oaccA[4], oaccB[4];
#pragma unroll
  for (int d = 0; d < 4; d++) { oaccA[d] = {0.f, 0.f, 0.f, 0.f}; oaccB[d] = {0.f, 0.f, 0.f, 0.f}; }
  float mstA = -INFINITY, lstA = 0.f;
  float mstB = -INFINITY, lstB = 0.f;

  // softmax for one half: mask, online max (defer-max), exp2, sum, pack pf
  auto SOFTMAX = [&](f32x4* sf, bool diag, int qg_, int kv0, float& mst, float& lst,
                     f32x4* oacc, hv8* pf) {
    float p[4][4];
#pragma unroll
    for (int nf = 0; nf < 4; nf++)
#pragma unroll
      for (int j = 0; j < 4; j++) {
        float x = sf[nf][j];
        if (diag && (kv0 + nf * 16 + g * 4 + j > qg_)) x = -INFINITY;
        p[nf][j] = x;
      }
    float rm = p[0][0];
#pragma unroll
    for (int nf = 0; nf < 4; nf++)
#pragma unroll
      for (int j = 0; j < 4; j++) rm = fmaxf(rm, p[nf][j]);
    rm = fmaxf(rm, __shfl_xor(rm, 16));
    rm = fmaxf(rm, __shfl_xor(rm, 32));
    if (!__all(rm <= mst + 8.0f)) {
      const float mn = fmaxf(mst, rm);
      const float corr = exp2f(mst - mn);  // first tile: exp2(-inf)=0
      lst *= corr;
#pragma unroll
      for (int d = 0; d < 4; d++) oacc[d] *= corr;
      mst = mn;
    }
    float rs = 0.f;
#pragma unroll
    for (int nf = 0; nf < 4; nf++)
#pragma unroll
      for (int j = 0; j < 4; j++) {
        p[nf][j] = exp2f(p[nf][j] - mst);
        rs += p[nf][j];
      }
    rs += __shfl_xor(rs, 16);
    rs += __shfl_xor(rs, 32);
    lst += rs;
    // pf[ks][i] = P[qg][kv0 + ks*32 + (i>>2)*16 + g*4 + (i&3)]  (pi-permuted, lane-local)
#pragma unroll
    for (int ks = 0; ks < 2; ks++) {
      const auto c0 = __builtin_amdgcn_cvt_pkrtz(p[2 * ks][0], p[2 * ks][1]);
      const auto c1 = __builtin_amdgcn_cvt_pkrtz(p[2 * ks][2], p[2 * ks][3]);
      const auto c2 = __builtin_amdgcn_cvt_pkrtz(p[2 * ks + 1][0], p[2 * ks + 1][1]);
      const auto c3 = __builtin_amdgcn_cvt_pkrtz(p[2 * ks + 1][2], p[2 * ks + 1][3]);
      pf[ks][0] = (_Float16)c0[0]; pf[ks][1] = (_Float16)c0[1];
      pf[ks][2] = (_Float16)c1[0]; pf[ks][3] = (_Float16)c1[1];
      pf[ks][4] = (_Float16)c2[0]; pf[ks][5] = (_Float16)c2[1];
      pf[ks][6] = (_Float16)c3[0]; pf[ks][7] = (_Float16)c3[1];
    }
  };

  const int ntB = qtB + 1;
  STAGE(0, 0);
  int cur = 0;

  for (int tt = 0; tt < ntB; tt++) {
    __syncthreads();  // implicit vmcnt(0): tile tt staged; buffer cur^1 free
    if (tt + 1 < ntB) STAGE((tt + 1) * 64, cur ^ 1);
    const int kv0 = tt * 64;
    const _Float16* Kb = Ks[cur];
    const _Float16* Vb = Vs[cur];
    const bool aAct = (tt <= qtA);

    // S^T = K Q^T for both halves: each kf fragment loaded once, feeds 2 MFMAs
    f32x4 sfA[4], sfB[4];
#pragma unroll
    for (int nf = 0; nf < 4; nf++) { sfA[nf] = {0.f, 0.f, 0.f, 0.f}; sfB[nf] = {0.f, 0.f, 0.f, 0.f}; }
#pragma unroll
    for (int ks = 0; ks < 2; ks++)
#pragma unroll
      for (int nf = 0; nf < 4; nf++) {
        const hv8 kf = *reinterpret_cast<const hv8*>(
            Kb + (nf * 16 + lr) * 64 + (((ks * 4 + g) ^ (lr & 7)) * 8));
        sfB[nf] = __builtin_amdgcn_mfma_f32_16x16x32_f16(kf, qfB[ks], sfB[nf], 0, 0, 0);
        if (aAct) sfA[nf] = __builtin_amdgcn_mfma_f32_16x16x32_f16(kf, qfA[ks], sfA[nf], 0, 0, 0);
      }

    hv8 pfA[2], pfB[2];
    SOFTMAX(sfB, tt == qtB, qgB, kv0, mstB, lstB, oaccB, pfB);
    if (aAct) SOFTMAX(sfA, tt == qtA, qgA, kv0, mstA, lstA, oaccA, pfA);

    // O^T += V^T P^T for both halves: each vtf fragment loaded once, feeds 2 MFMAs
#pragma unroll
    for (int dblk = 0; dblk < 4; dblk++) {
      const int row = dblk * 16 + lr;
#pragma unroll
      for (int ks = 0; ks < 2; ks++) {
        const hv8 vtf = *reinterpret_cast<const hv8*>(
            Vb + row * 64 + (((ks * 4 + g) ^ (row & 7)) * 8));
        oaccB[dblk] = __builtin_amdgcn_mfma_f32_16x16x32_f16(vtf, pfB[ks], oaccB[dblk], 0, 0, 0);
        if (aAct) oaccA[dblk] = __builtin_amdgcn_mfma_f32_16x16x32_f16(vtf, pfA[ks], oaccA[dblk], 0, 0, 0);
      }
    }
    cur ^= 1;
  }

  // epilogues: oacc[dblk][j] = O^T[d=dblk*16+g*4+j][qg] -> 8B stores
  {
    const float inv = 1.0f / lstB;
#pragma unroll
    for (int dblk = 0; dblk < 4; dblk++) {
      hv4 o;
#pragma unroll
      for (int j = 0; j < 4; j++) o[j] = (_Float16)(oaccB[dblk][j] * inv);
      *reinterpret_cast<hv4*>(Op + (size_t)qgB * 1024 + dblk * 16 + g * 4) = o;
    }
  }
  {
    const float inv = 1.0f / lstA;
#pragma unroll
    for (int dblk = 0; dblk < 4; dblk++) {
      hv4 o;
#pragma unroll
      for (int j = 0; j < 4; j++) o[j] = (_Float16)(oaccA[dblk][j] * inv);
      *reinterpret_cast<hv4*>(Op + (size_t)qgA * 1024 + dblk * 16 + g * 4) = o;
    }
  }
}

extern "C" void kernel_launch(void* const* d_in, const int* in_sizes, int n_in,
                              void* d_out, int out_size, void* d_ws, size_t ws_size,
                              hipStream_t stream) {
  const float* x = (const float*)d_in[0];
  const float* wq = (const float*)d_in[1];
  const float* wk = (const float*)d_in[2];
  const float* wv = (const float*)d_in[3];
  const float* wo = (const float*)d_in[4];
  float* out = (float*)d_out;
  char* ws = (char*)d_ws;
  const size_t MB = 1ull << 20;
  _Float16* xb   = (_Float16*)(ws + 0 * MB);   // 8 MB (A operand for QKV gemm)
  _Float16* wqkv = (_Float16*)(ws + 8 * MB);   // 6 MB (wq|wk|wv contiguous rows)
  _Float16* wob  = (_Float16*)(ws + 14 * MB);  // 2 MB
  _Float16* QKV  = (_Float16*)(ws + 16 * MB);  // 24 MB [4096][3072]
  _Float16* Vtb  = (_Float16*)(ws + 40 * MB);  // 8 MB  [32][64][2048] pi-permuted
  _Float16* Ab   = (_Float16*)(ws + 0 * MB);   // 8 MB  (reuses xb after QKV gemm)

  cvt_kernel<<<2048, 256, 0, stream>>>(x, xb, 4194304);
  cvt_w_kernel<<<4096, 256, 0, stream>>>(wq, wk, wv, wo, wqkv, wob);

  // fused Q|K|V projection: [4096][3072]
  gemm_nt<128, _Float16><<<dim3(24, 32), 256, 0, stream>>>(xb, wqkv, QKV, 4096, 3072, 1024);

  rope_kernel<<<16384, 256, 0, stream>>>(QKV);
  vtrans_kernel<<<dim3(32, 32), 256, 0, stream>>>(QKV, Vtb);

  attn_kernel<<<dim3(16, 32), 256, 0, stream>>>(QKV, Vtb, Ab);

  gemm_nt<64, float><<<dim3(8, 64), 256, 0, stream>>>(Ab, wob, out, 4096, 1024, 1024);
}

// Round 9
// 156.350 us; speedup vs baseline: 1.1814x; 1.0292x over previous
//
#include <hip/hip_runtime.h>
#include <math.h>

typedef _Float16 hv8 __attribute__((ext_vector_type(8)));
typedef _Float16 hv4 __attribute__((ext_vector_type(4)));
typedef _Float16 hv2 __attribute__((ext_vector_type(2)));
typedef float f32x4 __attribute__((ext_vector_type(4)));

#define LDS_AS(p) ((__attribute__((address_space(3))) void*)(p))
#define GLB_AS(p) ((const __attribute__((address_space(1))) void*)(p))

// ---------------- fp32 -> fp16 convert (x) ----------------
__global__ void cvt_kernel(const float* __restrict__ in, _Float16* __restrict__ out, int n) {
  int i = (blockIdx.x * blockDim.x + threadIdx.x) * 4;
  const int stride = gridDim.x * blockDim.x * 4;
  for (; i < n; i += stride) {
    const float4 v = *reinterpret_cast<const float4*>(in + i);
    hv4 o = {(_Float16)v.x, (_Float16)v.y, (_Float16)v.z, (_Float16)v.w};
    *reinterpret_cast<hv4*>(out + i) = o;
  }
}

// ---------------- fp32 -> fp16 convert, all 4 weights in one launch ----------------
__global__ void cvt_w_kernel(const float* __restrict__ wq, const float* __restrict__ wk,
                             const float* __restrict__ wv, const float* __restrict__ wo,
                             _Float16* __restrict__ wqkv, _Float16* __restrict__ wob) {
  const int i = (blockIdx.x * blockDim.x + threadIdx.x) * 4;  // 0 .. 4M-4
  const int seg = i >> 20;  // uniform per block (1M-elem segments)
  const int r = i & 1048575;
  const float* s = (seg == 0) ? wq : (seg == 1) ? wk : (seg == 2) ? wv : wo;
  _Float16* d = (seg < 3) ? (wqkv + (size_t)seg * 1048576) : wob;
  const float4 v = *reinterpret_cast<const float4*>(s + r);
  hv4 o = {(_Float16)v.x, (_Float16)v.y, (_Float16)v.z, (_Float16)v.w};
  *reinterpret_cast<hv4*>(d + r) = o;
}

// ---------------- RoPE in-place on fused QKV [4096][3072]; Q|K = cols 0..2047 ----------------
__global__ void rope_kernel(_Float16* __restrict__ T) {
  const int idx = blockIdx.x * blockDim.x + threadIdx.x;
  const int pair = idx & 1023;  // hh*32 + i
  const int row = idx >> 10;    // b*2048 + pos
  const int pos = row & 2047;
  const int hh = pair >> 5, i = pair & 31;
  const float freq = exp2f((float)i * (-13.287712379549449f / 32.0f));
  const float ang = (float)pos * freq;
  float s, c;
  sincosf(ang, &s, &c);
  const size_t off = (size_t)row * 3072 + hh * 64 + 2 * i;
  hv2 v = *reinterpret_cast<const hv2*>(T + off);
  const float e = (float)v[0];
  const float o = (float)v[1];
  v[0] = (_Float16)(e * c - o * s);
  v[1] = (_Float16)(e * s + o * c);
  *reinterpret_cast<hv2*>(T + off) = v;
}

// ---------------- V transpose with pi-permuted kv storage ----------------
// For kv = ks*32 + hi*16 + g*4 + lo  ->  slot s = ks*32 + g*8 + hi*4 + lo (within 64-block).
// Makes attn's PV A-fragment a single contiguous b128 read (verified: 0 bank conflicts).
__global__ __launch_bounds__(256) void vtrans_kernel(const _Float16* __restrict__ QKV,
                                                     _Float16* __restrict__ Vt) {
  __shared__ __align__(16) _Float16 Ts[64][72];
  const int t = threadIdx.x;
  const int n0 = blockIdx.x * 64;
  const int bh = blockIdx.y;
  const int b = bh >> 4, h = bh & 15;
  const _Float16* src = QKV + (size_t)(b * 2048 + n0) * 3072 + 2048 + h * 64;
#pragma unroll
  for (int i = 0; i < 2; i++) {
    const int s = i * 256 + t, r = s >> 3, c = (s & 7) * 8;
    *reinterpret_cast<hv8*>(&Ts[r][c]) = *reinterpret_cast<const hv8*>(src + (size_t)r * 3072 + c);
  }
  __syncthreads();
  _Float16* dst = Vt + (size_t)bh * 64 * 2048 + n0;
#pragma unroll
  for (int i = 0; i < 2; i++) {
    const int s = i * 256 + t, c = s >> 3, r0 = (s & 7) * 8;  // kv rows r0..r0+7, col d=c
    const int base0 = (r0 & 32) + ((r0 & 8) ? 16 : 0) + ((r0 & 16) ? 4 : 0);
    hv4 o0, o1;
#pragma unroll
    for (int k = 0; k < 4; k++) { o0[k] = Ts[r0 + k][c]; o1[k] = Ts[r0 + 4 + k][c]; }
    *reinterpret_cast<hv4*>(dst + (size_t)c * 2048 + base0) = o0;
    *reinterpret_cast<hv4*>(dst + (size_t)c * 2048 + base0 + 8) = o1;
  }
}

// ---------------- NT GEMM: C[m][n] = sum_k A[m][k] * B[n][k] ---------------- (unchanged)
template <int BM, typename OutT>
__global__ __launch_bounds__(256) void gemm_nt(const _Float16* __restrict__ A,
                                               const _Float16* __restrict__ B,
                                               OutT* __restrict__ C,
                                               const int M, const int N, const int K) {
  constexpr int MI = BM / 32;
  constexpr int ALOADS = BM / 64;
  __shared__ __align__(16) _Float16 As[BM * 32];
  __shared__ __align__(16) _Float16 Bs[128 * 32];
  const int t = threadIdx.x;
  const int w = t >> 6, lane = t & 63;
  const int wr = w >> 1, wc = w & 1;
  const int g = lane >> 4, lr = lane & 15;
  const int mBase = blockIdx.y * BM, nBase = blockIdx.x * 128;

  f32x4 acc[MI][4];
#pragma unroll
  for (int a = 0; a < MI; a++)
#pragma unroll
    for (int bb = 0; bb < 4; bb++) acc[a][bb] = {0.f, 0.f, 0.f, 0.f};

  const int srow = t >> 2;
  const int scol = (t & 3) * 8;
  for (int k0 = 0; k0 < K; k0 += 32) {
#pragma unroll
    for (int i = 0; i < ALOADS; i++) {
      const _Float16* ga = A + (size_t)(mBase + i * 64 + srow) * K + k0 + scol;
      __builtin_amdgcn_global_load_lds(GLB_AS(ga), LDS_AS(As + (i * 256 + w * 64) * 8), 16, 0, 0);
    }
#pragma unroll
    for (int i = 0; i < 2; i++) {
      const _Float16* gb = B + (size_t)(nBase + i * 64 + srow) * K + k0 + scol;
      __builtin_amdgcn_global_load_lds(GLB_AS(gb), LDS_AS(Bs + (i * 256 + w * 64) * 8), 16, 0, 0);
    }
    __syncthreads();
    hv8 af[MI], bfr[4];
#pragma unroll
    for (int mi = 0; mi < MI; mi++)
      af[mi] = *reinterpret_cast<const hv8*>(As + (wr * (BM / 2) + mi * 16 + lr) * 32 + g * 8);
#pragma unroll
    for (int ni = 0; ni < 4; ni++)
      bfr[ni] = *reinterpret_cast<const hv8*>(Bs + (wc * 64 + ni * 16 + lr) * 32 + g * 8);
#pragma unroll
    for (int mi = 0; mi < MI; mi++)
#pragma unroll
      for (int ni = 0; ni < 4; ni++)
        acc[mi][ni] = __builtin_amdgcn_mfma_f32_16x16x32_f16(af[mi], bfr[ni], acc[mi][ni], 0, 0, 0);
    __syncthreads();
  }
#pragma unroll
  for (int mi = 0; mi < MI; mi++) {
#pragma unroll
    for (int j = 0; j < 4; j++) {
      const size_t row = mBase + wr * (BM / 2) + mi * 16 + g * 4 + j;
#pragma unroll
      for (int ni = 0; ni < 4; ni++) {
        const int col = nBase + wc * 64 + ni * 16 + lr;
        C[row * N + col] = (OutT)acc[mi][ni][j];
      }
    }
  }
}

// ---------------- flash causal attention, fold-pair balanced, shfl-free softmax ----------------
// Block x in [0,16): q-tiles qtA=x (light) + qtB=31-x (heavy), one shared KV sweep (33 tile-
// computes/block under any dispatch). Swapped QK^T (S^T = K Q^T), double-buffered staging,
// pi-permuted Vt -> b128 PV A-frags. Softmax steady state has ZERO cross-lane ops:
//  - ballot-gated defer-max: in-lane max tree + __all(rm <= mst+8); cross-lane reduce only
//    on failure (first tile / rare growth). P bounded by 2^8, fp16-safe.
//  - row-sum via MFMA with A=ones: lacc[j] accumulates sum_k P[k][q] lane-locally.
__global__ __launch_bounds__(256) void attn_kernel(const _Float16* __restrict__ QKV,
                                                   const _Float16* __restrict__ Vt,
                                                   _Float16* __restrict__ O) {
  __shared__ __align__(16) _Float16 Ks[2][64 * 64];
  __shared__ __align__(16) _Float16 Vs[2][64 * 64];
  const int t = threadIdx.x;
  const int w = t >> 6, lane = t & 63;
  const int g = lane >> 4, lr = lane & 15;
  const int qtA = blockIdx.x;        // 0..15  (light q-tile)
  const int qtB = 31 - qtA;          // 16..31 (heavy q-tile)
  const int m0A = qtA * 64, m0B = qtB * 64;
  const int bh = blockIdx.y;
  const int b = bh >> 4, h = bh & 15;
  const _Float16* Qp = QKV + (size_t)b * 2048 * 3072 + h * 64;
  const _Float16* Kp = Qp + 1024;
  const _Float16* Vp = Vt + (size_t)bh * 64 * 2048;
  _Float16* Op = O + (size_t)b * 2048 * 1024 + h * 64;

  const int qgA = m0A + w * 16 + lr;
  const int qgB = m0B + w * 16 + lr;

  // Q B-frags (n=q, k=g*8+i), pre-scaled by (1/8)*log2(e) for exp2-domain softmax
  hv8 qfA[2], qfB[2];
#pragma unroll
  for (int ks = 0; ks < 2; ks++) {
    qfA[ks] = *reinterpret_cast<const hv8*>(Qp + (size_t)qgA * 3072 + ks * 32 + g * 8);
    qfA[ks] = qfA[ks] * (_Float16)0.18033688f;
    qfB[ks] = *reinterpret_cast<const hv8*>(Qp + (size_t)qgB * 3072 + ks * 32 + g * 8);
    qfB[ks] = qfB[ks] * (_Float16)0.18033688f;
  }

  const hv8 onesf = {(_Float16)1.0f, (_Float16)1.0f, (_Float16)1.0f, (_Float16)1.0f,
                     (_Float16)1.0f, (_Float16)1.0f, (_Float16)1.0f, (_Float16)1.0f};

  auto STAGE = [&](int kv0, int bi) {
#pragma unroll
    for (int i = 0; i < 2; i++) {
      const int s = i * 256 + t;
      const int r = s >> 3;
      const int cs = ((s & 7) ^ (r & 7)) * 8;
      __builtin_amdgcn_global_load_lds(GLB_AS(Kp + (size_t)(kv0 + r) * 3072 + cs),
                                       LDS_AS(&Ks[bi][s * 8]), 16, 0, 0);
      __builtin_amdgcn_global_load_lds(GLB_AS(Vp + (size_t)r * 2048 + kv0 + cs),
                                       LDS_AS(&Vs[bi][s * 8]), 16, 0, 0);
    }
  };

  f32x4 oaccA[4], oaccB[4];
#pragma unroll
  for (int d = 0; d < 4; d++) { oaccA[d] = {0.f, 0.f, 0.f, 0.f}; oaccB[d] = {0.f, 0.f, 0.f, 0.f}; }
  f32x4 laccA = {0.f, 0.f, 0.f, 0.f}, laccB = {0.f, 0.f, 0.f, 0.f};
  float mstA = -INFINITY, mstB = -INFINITY;

  // shfl-free steady-state softmax for one half; pf = pi-permuted fp16 P fragments
  auto SOFTMAX = [&](f32x4* sf, bool diag, int qg_, int kv0, float& mst,
                     f32x4* oacc, f32x4& lacc, hv8* pf) {
    float p[4][4];
#pragma unroll
    for (int nf = 0; nf < 4; nf++)
#pragma unroll
      for (int j = 0; j < 4; j++) {
        float x = sf[nf][j];
        if (diag && (kv0 + nf * 16 + g * 4 + j > qg_)) x = -INFINITY;
        p[nf][j] = x;
      }
    // in-lane max tree (15 fmax, depth 4; max3-fusable)
    float r4[4];
#pragma unroll
    for (int nf = 0; nf < 4; nf++)
      r4[nf] = fmaxf(fmaxf(p[nf][0], p[nf][1]), fmaxf(p[nf][2], p[nf][3]));
    const float rm = fmaxf(fmaxf(r4[0], r4[1]), fmaxf(r4[2], r4[3]));
    // ballot-gated rescale: wave-wide bound check, no shfl in steady state
    if (!__all(rm <= mst + 8.0f)) {
      float rw = fmaxf(rm, __shfl_xor(rm, 16));
      rw = fmaxf(rw, __shfl_xor(rw, 32));
      const float mn = fmaxf(mst, rw);
      const float corr = exp2f(mst - mn);  // first tile: exp2(-inf)=0
#pragma unroll
      for (int d = 0; d < 4; d++) oacc[d] *= corr;
      lacc *= corr;
      mst = mn;
    }
#pragma unroll
    for (int nf = 0; nf < 4; nf++)
#pragma unroll
      for (int j = 0; j < 4; j++) p[nf][j] = exp2f(p[nf][j] - mst);
    // pf[ks][i] = P[qg][kv0 + ks*32 + (i>>2)*16 + g*4 + (i&3)]  (pi-permuted, lane-local)
#pragma unroll
    for (int ks = 0; ks < 2; ks++) {
      const auto c0 = __builtin_amdgcn_cvt_pkrtz(p[2 * ks][0], p[2 * ks][1]);
      const auto c1 = __builtin_amdgcn_cvt_pkrtz(p[2 * ks][2], p[2 * ks][3]);
      const auto c2 = __builtin_amdgcn_cvt_pkrtz(p[2 * ks + 1][0], p[2 * ks + 1][1]);
      const auto c3 = __builtin_amdgcn_cvt_pkrtz(p[2 * ks + 1][2], p[2 * ks + 1][3]);
      pf[ks][0] = (_Float16)c0[0]; pf[ks][1] = (_Float16)c0[1];
      pf[ks][2] = (_Float16)c1[0]; pf[ks][3] = (_Float16)c1[1];
      pf[ks][4] = (_Float16)c2[0]; pf[ks][5] = (_Float16)c2[1];
      pf[ks][6] = (_Float16)c3[0]; pf[ks][7] = (_Float16)c3[1];
    }
  };

  const int ntB = qtB + 1;
  STAGE(0, 0);
  int cur = 0;

  for (int tt = 0; tt < ntB; tt++) {
    __syncthreads();  // implicit vmcnt(0): tile tt staged; buffer cur^1 free
    if (tt + 1 < ntB) STAGE((tt + 1) * 64, cur ^ 1);
    const int kv0 = tt * 64;
    const _Float16* Kb = Ks[cur];
    const _Float16* Vb = Vs[cur];
    const bool aAct = (tt <= qtA);

    // S^T = K Q^T for both halves: each kf fragment loaded once, feeds 2 MFMAs
    f32x4 sfA[4], sfB[4];
#pragma unroll
    for (int nf = 0; nf < 4; nf++) { sfA[nf] = {0.f, 0.f, 0.f, 0.f}; sfB[nf] = {0.f, 0.f, 0.f, 0.f}; }
#pragma unroll
    for (int ks = 0; ks < 2; ks++)
#pragma unroll
      for (int nf = 0; nf < 4; nf++) {
        const hv8 kf = *reinterpret_cast<const hv8*>(
            Kb + (nf * 16 + lr) * 64 + (((ks * 4 + g) ^ (lr & 7)) * 8));
        sfB[nf] = __builtin_amdgcn_mfma_f32_16x16x32_f16(kf, qfB[ks], sfB[nf], 0, 0, 0);
        if (aAct) sfA[nf] = __builtin_amdgcn_mfma_f32_16x16x32_f16(kf, qfA[ks], sfA[nf], 0, 0, 0);
      }

    hv8 pfA[2], pfB[2];
    SOFTMAX(sfB, tt == qtB, qgB, kv0, mstB, oaccB, laccB, pfB);
    if (aAct) SOFTMAX(sfA, tt == qtA, qgA, kv0, mstA, oaccA, laccA, pfA);

    // O^T += V^T P^T; row-sum via ones-MFMA (lane-local l accumulation)
#pragma unroll
    for (int dblk = 0; dblk < 4; dblk++) {
      const int row = dblk * 16 + lr;
#pragma unroll
      for (int ks = 0; ks < 2; ks++) {
        const hv8 vtf = *reinterpret_cast<const hv8*>(
            Vb + row * 64 + (((ks * 4 + g) ^ (row & 7)) * 8));
        oaccB[dblk] = __builtin_amdgcn_mfma_f32_16x16x32_f16(vtf, pfB[ks], oaccB[dblk], 0, 0, 0);
        if (aAct) oaccA[dblk] = __builtin_amdgcn_mfma_f32_16x16x32_f16(vtf, pfA[ks], oaccA[dblk], 0, 0, 0);
      }
    }
#pragma unroll
    for (int ks = 0; ks < 2; ks++) {
      laccB = __builtin_amdgcn_mfma_f32_16x16x32_f16(onesf, pfB[ks], laccB, 0, 0, 0);
      if (aAct) laccA = __builtin_amdgcn_mfma_f32_16x16x32_f16(onesf, pfA[ks], laccA, 0, 0, 0);
    }
    cur ^= 1;
  }

  // epilogues: oacc[dblk][j] = O^T[d=dblk*16+g*4+j][qg]; l = lacc[0] (rows equal by ones-A)
  {
    const float inv = 1.0f / laccB[0];
#pragma unroll
    for (int dblk = 0; dblk < 4; dblk++) {
      hv4 o;
#pragma unroll
      for (int j = 0; j < 4; j++) o[j] = (_Float16)(oaccB[dblk][j] * inv);
      *reinterpret_cast<hv4*>(Op + (size_t)qgB * 1024 + dblk * 16 + g * 4) = o;
    }
  }
  {
    const float inv = 1.0f / laccA[0];
#pragma unroll
    for (int dblk = 0; dblk < 4; dblk++) {
      hv4 o;
#pragma unroll
      for (int j = 0; j < 4; j++) o[j] = (_Float16)(oaccA[dblk][j] * inv);
      *reinterpret_cast<hv4*>(Op + (size_t)qgA * 1024 + dblk * 16 + g * 4) = o;
    }
  }
}

extern "C" void kernel_launch(void* const* d_in, const int* in_sizes, int n_in,
                              void* d_out, int out_size, void* d_ws, size_t ws_size,
                              hipStream_t stream) {
  const float* x = (const float*)d_in[0];
  const float* wq = (const float*)d_in[1];
  const float* wk = (const float*)d_in[2];
  const float* wv = (const float*)d_in[3];
  const float* wo = (const float*)d_in[4];
  float* out = (float*)d_out;
  char* ws = (char*)d_ws;
  const size_t MB = 1ull << 20;
  _Float16* xb   = (_Float16*)(ws + 0 * MB);   // 8 MB (A operand for QKV gemm)
  _Float16* wqkv = (_Float16*)(ws + 8 * MB);   // 6 MB (wq|wk|wv contiguous rows)
  _Float16* wob  = (_Float16*)(ws + 14 * MB);  // 2 MB
  _Float16* QKV  = (_Float16*)(ws + 16 * MB);  // 24 MB [4096][3072]
  _Float16* Vtb  = (_Float16*)(ws + 40 * MB);  // 8 MB  [32][64][2048] pi-permuted
  _Float16* Ab   = (_Float16*)(ws + 0 * MB);   // 8 MB  (reuses xb after QKV gemm)

  cvt_kernel<<<2048, 256, 0, stream>>>(x, xb, 4194304);
  cvt_w_kernel<<<4096, 256, 0, stream>>>(wq, wk, wv, wo, wqkv, wob);

  // fused Q|K|V projection: [4096][3072]
  gemm_nt<128, _Float16><<<dim3(24, 32), 256, 0, stream>>>(xb, wqkv, QKV, 4096, 3072, 1024);

  rope_kernel<<<16384, 256, 0, stream>>>(QKV);
  vtrans_kernel<<<dim3(32, 32), 256, 0, stream>>>(QKV, Vtb);

  attn_kernel<<<dim3(16, 32), 256, 0, stream>>>(QKV, Vtb, Ab);

  gemm_nt<64, float><<<dim3(8, 64), 256, 0, stream>>>(Ab, wob, out, 4096, 1024, 1024);
}

// Round 10
// 131.804 us; speedup vs baseline: 1.4014x; 1.1862x over previous
//
#include <hip/hip_runtime.h>
#include <math.h>

typedef _Float16 hv8 __attribute__((ext_vector_type(8)));
typedef _Float16 hv4 __attribute__((ext_vector_type(4)));
typedef _Float16 hv2 __attribute__((ext_vector_type(2)));
typedef float f32x4 __attribute__((ext_vector_type(4)));

#define LDS_AS(p) ((__attribute__((address_space(3))) void*)(p))
#define GLB_AS(p) ((const __attribute__((address_space(1))) void*)(p))

// single-instruction base-2 exp (bypasses OCML; v_exp_f32 is the native trans op)
__device__ __forceinline__ float fexp2(float x) {
  float r;
  asm("v_exp_f32 %0, %1" : "=v"(r) : "v"(x));
  return r;
}

// ---------------- fp32 -> fp16 convert (x) ----------------
__global__ void cvt_kernel(const float* __restrict__ in, _Float16* __restrict__ out, int n) {
  int i = (blockIdx.x * blockDim.x + threadIdx.x) * 4;
  const int stride = gridDim.x * blockDim.x * 4;
  for (; i < n; i += stride) {
    const float4 v = *reinterpret_cast<const float4*>(in + i);
    hv4 o = {(_Float16)v.x, (_Float16)v.y, (_Float16)v.z, (_Float16)v.w};
    *reinterpret_cast<hv4*>(out + i) = o;
  }
}

// ---------------- fp32 -> fp16 convert, all 4 weights in one launch ----------------
__global__ void cvt_w_kernel(const float* __restrict__ wq, const float* __restrict__ wk,
                             const float* __restrict__ wv, const float* __restrict__ wo,
                             _Float16* __restrict__ wqkv, _Float16* __restrict__ wob) {
  const int i = (blockIdx.x * blockDim.x + threadIdx.x) * 4;  // 0 .. 4M-4
  const int seg = i >> 20;  // uniform per block (1M-elem segments)
  const int r = i & 1048575;
  const float* s = (seg == 0) ? wq : (seg == 1) ? wk : (seg == 2) ? wv : wo;
  _Float16* d = (seg < 3) ? (wqkv + (size_t)seg * 1048576) : wob;
  const float4 v = *reinterpret_cast<const float4*>(s + r);
  hv4 o = {(_Float16)v.x, (_Float16)v.y, (_Float16)v.z, (_Float16)v.w};
  *reinterpret_cast<hv4*>(d + r) = o;
}

// ---------------- RoPE in-place on fused QKV [4096][3072]; Q|K = cols 0..2047 ----------------
__global__ void rope_kernel(_Float16* __restrict__ T) {
  const int idx = blockIdx.x * blockDim.x + threadIdx.x;
  const int pair = idx & 1023;  // hh*32 + i
  const int row = idx >> 10;    // b*2048 + pos
  const int pos = row & 2047;
  const int hh = pair >> 5, i = pair & 31;
  const float freq = exp2f((float)i * (-13.287712379549449f / 32.0f));
  const float ang = (float)pos * freq;
  float s, c;
  sincosf(ang, &s, &c);
  const size_t off = (size_t)row * 3072 + hh * 64 + 2 * i;
  hv2 v = *reinterpret_cast<const hv2*>(T + off);
  const float e = (float)v[0];
  const float o = (float)v[1];
  v[0] = (_Float16)(e * c - o * s);
  v[1] = (_Float16)(e * s + o * c);
  *reinterpret_cast<hv2*>(T + off) = v;
}

// ---------------- V transpose with pi-permuted kv storage ----------------
// For kv = ks*32 + hi*16 + g*4 + lo  ->  slot s = ks*32 + g*8 + hi*4 + lo (within 64-block).
// Makes attn's PV A-fragment a single contiguous b128 read (verified: 0 bank conflicts).
__global__ __launch_bounds__(256) void vtrans_kernel(const _Float16* __restrict__ QKV,
                                                     _Float16* __restrict__ Vt) {
  __shared__ __align__(16) _Float16 Ts[64][72];
  const int t = threadIdx.x;
  const int n0 = blockIdx.x * 64;
  const int bh = blockIdx.y;
  const int b = bh >> 4, h = bh & 15;
  const _Float16* src = QKV + (size_t)(b * 2048 + n0) * 3072 + 2048 + h * 64;
#pragma unroll
  for (int i = 0; i < 2; i++) {
    const int s = i * 256 + t, r = s >> 3, c = (s & 7) * 8;
    *reinterpret_cast<hv8*>(&Ts[r][c]) = *reinterpret_cast<const hv8*>(src + (size_t)r * 3072 + c);
  }
  __syncthreads();
  _Float16* dst = Vt + (size_t)bh * 64 * 2048 + n0;
#pragma unroll
  for (int i = 0; i < 2; i++) {
    const int s = i * 256 + t, c = s >> 3, r0 = (s & 7) * 8;  // kv rows r0..r0+7, col d=c
    const int base0 = (r0 & 32) + ((r0 & 8) ? 16 : 0) + ((r0 & 16) ? 4 : 0);
    hv4 o0, o1;
#pragma unroll
    for (int k = 0; k < 4; k++) { o0[k] = Ts[r0 + k][c]; o1[k] = Ts[r0 + 4 + k][c]; }
    *reinterpret_cast<hv4*>(dst + (size_t)c * 2048 + base0) = o0;
    *reinterpret_cast<hv4*>(dst + (size_t)c * 2048 + base0 + 8) = o1;
  }
}

// ---------------- NT GEMM: C[m][n] = sum_k A[m][k] * B[n][k] ---------------- (unchanged)
template <int BM, typename OutT>
__global__ __launch_bounds__(256) void gemm_nt(const _Float16* __restrict__ A,
                                               const _Float16* __restrict__ B,
                                               OutT* __restrict__ C,
                                               const int M, const int N, const int K) {
  constexpr int MI = BM / 32;
  constexpr int ALOADS = BM / 64;
  __shared__ __align__(16) _Float16 As[BM * 32];
  __shared__ __align__(16) _Float16 Bs[128 * 32];
  const int t = threadIdx.x;
  const int w = t >> 6, lane = t & 63;
  const int wr = w >> 1, wc = w & 1;
  const int g = lane >> 4, lr = lane & 15;
  const int mBase = blockIdx.y * BM, nBase = blockIdx.x * 128;

  f32x4 acc[MI][4];
#pragma unroll
  for (int a = 0; a < MI; a++)
#pragma unroll
    for (int bb = 0; bb < 4; bb++) acc[a][bb] = {0.f, 0.f, 0.f, 0.f};

  const int srow = t >> 2;
  const int scol = (t & 3) * 8;
  for (int k0 = 0; k0 < K; k0 += 32) {
#pragma unroll
    for (int i = 0; i < ALOADS; i++) {
      const _Float16* ga = A + (size_t)(mBase + i * 64 + srow) * K + k0 + scol;
      __builtin_amdgcn_global_load_lds(GLB_AS(ga), LDS_AS(As + (i * 256 + w * 64) * 8), 16, 0, 0);
    }
#pragma unroll
    for (int i = 0; i < 2; i++) {
      const _Float16* gb = B + (size_t)(nBase + i * 64 + srow) * K + k0 + scol;
      __builtin_amdgcn_global_load_lds(GLB_AS(gb), LDS_AS(Bs + (i * 256 + w * 64) * 8), 16, 0, 0);
    }
    __syncthreads();
    hv8 af[MI], bfr[4];
#pragma unroll
    for (int mi = 0; mi < MI; mi++)
      af[mi] = *reinterpret_cast<const hv8*>(As + (wr * (BM / 2) + mi * 16 + lr) * 32 + g * 8);
#pragma unroll
    for (int ni = 0; ni < 4; ni++)
      bfr[ni] = *reinterpret_cast<const hv8*>(Bs + (wc * 64 + ni * 16 + lr) * 32 + g * 8);
#pragma unroll
    for (int mi = 0; mi < MI; mi++)
#pragma unroll
      for (int ni = 0; ni < 4; ni++)
        acc[mi][ni] = __builtin_amdgcn_mfma_f32_16x16x32_f16(af[mi], bfr[ni], acc[mi][ni], 0, 0, 0);
    __syncthreads();
  }
#pragma unroll
  for (int mi = 0; mi < MI; mi++) {
#pragma unroll
    for (int j = 0; j < 4; j++) {
      const size_t row = mBase + wr * (BM / 2) + mi * 16 + g * 4 + j;
#pragma unroll
      for (int ni = 0; ni < 4; ni++) {
        const int col = nBase + wc * 64 + ni * 16 + lr;
        C[row * N + col] = (OutT)acc[mi][ni][j];
      }
    }
  }
}

// ---------------- flash causal attention, fold-pair balanced, split-half pipelines ----------------
// Block x in [0,16): q-tiles qtA=x (light) + qtB=31-x (heavy), one shared KV sweep (33 tile-
// computes/block). Per tile each half runs a COMPLETE pipeline {QK -> softmax -> PV} before
// the other half starts: halves peak register liveness (one sf/p/pf set live at a time; no
// AGPR shuttling) and lets PV(B) MFMAs overlap SM(A) VALU. __launch_bounds__(256,2) gives the
// compiler the full 2-wave/SIMD VGPR budget (grid caps occupancy at 2 blocks/CU anyway).
// Softmax: ballot-gated defer-max (no shfl steady state), single-instr v_exp_f32,
// row-sum via ones-MFMA. pi-permuted Vt -> b128 PV A-frags (0 bank conflicts).
__global__ __launch_bounds__(256, 2) void attn_kernel(const _Float16* __restrict__ QKV,
                                                      const _Float16* __restrict__ Vt,
                                                      _Float16* __restrict__ O) {
  __shared__ __align__(16) _Float16 Ks[2][64 * 64];
  __shared__ __align__(16) _Float16 Vs[2][64 * 64];
  const int t = threadIdx.x;
  const int w = t >> 6, lane = t & 63;
  const int g = lane >> 4, lr = lane & 15;
  const int qtA = blockIdx.x;        // 0..15  (light q-tile)
  const int qtB = 31 - qtA;          // 16..31 (heavy q-tile)
  const int m0A = qtA * 64, m0B = qtB * 64;
  const int bh = blockIdx.y;
  const int b = bh >> 4, h = bh & 15;
  const _Float16* Qp = QKV + (size_t)b * 2048 * 3072 + h * 64;
  const _Float16* Kp = Qp + 1024;
  const _Float16* Vp = Vt + (size_t)bh * 64 * 2048;
  _Float16* Op = O + (size_t)b * 2048 * 1024 + h * 64;

  const int qgA = m0A + w * 16 + lr;
  const int qgB = m0B + w * 16 + lr;

  // Q B-frags (n=q, k=g*8+i), pre-scaled by (1/8)*log2(e) for exp2-domain softmax
  hv8 qfA[2], qfB[2];
#pragma unroll
  for (int ks = 0; ks < 2; ks++) {
    qfA[ks] = *reinterpret_cast<const hv8*>(Qp + (size_t)qgA * 3072 + ks * 32 + g * 8);
    qfA[ks] = qfA[ks] * (_Float16)0.18033688f;
    qfB[ks] = *reinterpret_cast<const hv8*>(Qp + (size_t)qgB * 3072 + ks * 32 + g * 8);
    qfB[ks] = qfB[ks] * (_Float16)0.18033688f;
  }

  const hv8 onesf = {(_Float16)1.0f, (_Float16)1.0f, (_Float16)1.0f, (_Float16)1.0f,
                     (_Float16)1.0f, (_Float16)1.0f, (_Float16)1.0f, (_Float16)1.0f};

  auto STAGE = [&](int kv0, int bi) {
#pragma unroll
    for (int i = 0; i < 2; i++) {
      const int s = i * 256 + t;
      const int r = s >> 3;
      const int cs = ((s & 7) ^ (r & 7)) * 8;
      __builtin_amdgcn_global_load_lds(GLB_AS(Kp + (size_t)(kv0 + r) * 3072 + cs),
                                       LDS_AS(&Ks[bi][s * 8]), 16, 0, 0);
      __builtin_amdgcn_global_load_lds(GLB_AS(Vp + (size_t)r * 2048 + kv0 + cs),
                                       LDS_AS(&Vs[bi][s * 8]), 16, 0, 0);
    }
  };

  f32x4 oaccA[4], oaccB[4];
#pragma unroll
  for (int d = 0; d < 4; d++) { oaccA[d] = {0.f, 0.f, 0.f, 0.f}; oaccB[d] = {0.f, 0.f, 0.f, 0.f}; }
  f32x4 laccA = {0.f, 0.f, 0.f, 0.f}, laccB = {0.f, 0.f, 0.f, 0.f};
  float mstA = -INFINITY, mstB = -INFINITY;

  // complete pipeline for one half: QK^T -> softmax -> PV (+ ones-MFMA row-sum)
  auto HALF = [&](const _Float16* Kb, const _Float16* Vb, const hv8* qf, bool diag,
                  int qg_, int kv0, float& mst, f32x4* oacc, f32x4& lacc) {
    // S^T = K Q^T : A = K rows (m=kv), B = Q (n=q)
    f32x4 sf[4];
#pragma unroll
    for (int nf = 0; nf < 4; nf++) sf[nf] = {0.f, 0.f, 0.f, 0.f};
#pragma unroll
    for (int ks = 0; ks < 2; ks++)
#pragma unroll
      for (int nf = 0; nf < 4; nf++) {
        const hv8 kf = *reinterpret_cast<const hv8*>(
            Kb + (nf * 16 + lr) * 64 + (((ks * 4 + g) ^ (lr & 7)) * 8));
        sf[nf] = __builtin_amdgcn_mfma_f32_16x16x32_f16(kf, qf[ks], sf[nf], 0, 0, 0);
      }
    // softmax (base-2, in-register, shfl-free steady state)
    float p[4][4];
#pragma unroll
    for (int nf = 0; nf < 4; nf++)
#pragma unroll
      for (int j = 0; j < 4; j++) {
        float x = sf[nf][j];
        if (diag && (kv0 + nf * 16 + g * 4 + j > qg_)) x = -INFINITY;
        p[nf][j] = x;
      }
    float r4[4];
#pragma unroll
    for (int nf = 0; nf < 4; nf++)
      r4[nf] = fmaxf(fmaxf(p[nf][0], p[nf][1]), fmaxf(p[nf][2], p[nf][3]));
    const float rm = fmaxf(fmaxf(r4[0], r4[1]), fmaxf(r4[2], r4[3]));
    if (!__all(rm <= mst + 8.0f)) {
      float rw = fmaxf(rm, __shfl_xor(rm, 16));
      rw = fmaxf(rw, __shfl_xor(rw, 32));
      const float mn = fmaxf(mst, rw);
      const float corr = fexp2(mst - mn);  // first tile: exp2(-inf)=0
#pragma unroll
      for (int d = 0; d < 4; d++) oacc[d] *= corr;
      lacc *= corr;
      mst = mn;
    }
#pragma unroll
    for (int nf = 0; nf < 4; nf++)
#pragma unroll
      for (int j = 0; j < 4; j++) p[nf][j] = fexp2(p[nf][j] - mst);
    // pf[ks][i] = P[qg][kv0 + ks*32 + (i>>2)*16 + g*4 + (i&3)]  (pi-permuted, lane-local)
    hv8 pf[2];
#pragma unroll
    for (int ks = 0; ks < 2; ks++) {
      const auto c0 = __builtin_amdgcn_cvt_pkrtz(p[2 * ks][0], p[2 * ks][1]);
      const auto c1 = __builtin_amdgcn_cvt_pkrtz(p[2 * ks][2], p[2 * ks][3]);
      const auto c2 = __builtin_amdgcn_cvt_pkrtz(p[2 * ks + 1][0], p[2 * ks + 1][1]);
      const auto c3 = __builtin_amdgcn_cvt_pkrtz(p[2 * ks + 1][2], p[2 * ks + 1][3]);
      pf[ks][0] = (_Float16)c0[0]; pf[ks][1] = (_Float16)c0[1];
      pf[ks][2] = (_Float16)c1[0]; pf[ks][3] = (_Float16)c1[1];
      pf[ks][4] = (_Float16)c2[0]; pf[ks][5] = (_Float16)c2[1];
      pf[ks][6] = (_Float16)c3[0]; pf[ks][7] = (_Float16)c3[1];
    }
    // O^T += V^T P^T ; l += ones * P
#pragma unroll
    for (int dblk = 0; dblk < 4; dblk++) {
      const int row = dblk * 16 + lr;
#pragma unroll
      for (int ks = 0; ks < 2; ks++) {
        const hv8 vtf = *reinterpret_cast<const hv8*>(
            Vb + row * 64 + (((ks * 4 + g) ^ (row & 7)) * 8));
        oacc[dblk] = __builtin_amdgcn_mfma_f32_16x16x32_f16(vtf, pf[ks], oacc[dblk], 0, 0, 0);
      }
    }
#pragma unroll
    for (int ks = 0; ks < 2; ks++)
      lacc = __builtin_amdgcn_mfma_f32_16x16x32_f16(onesf, pf[ks], lacc, 0, 0, 0);
  };

  const int ntB = qtB + 1;
  STAGE(0, 0);
  int cur = 0;

  for (int tt = 0; tt < ntB; tt++) {
    __syncthreads();  // implicit vmcnt(0): tile tt staged; buffer cur^1 free
    if (tt + 1 < ntB) STAGE((tt + 1) * 64, cur ^ 1);
    const int kv0 = tt * 64;
    const _Float16* Kb = Ks[cur];
    const _Float16* Vb = Vs[cur];

    HALF(Kb, Vb, qfB, tt == qtB, qgB, kv0, mstB, oaccB, laccB);
    if (tt <= qtA) HALF(Kb, Vb, qfA, tt == qtA, qgA, kv0, mstA, oaccA, laccA);
    cur ^= 1;
  }

  // epilogues: oacc[dblk][j] = O^T[d=dblk*16+g*4+j][qg]; l = lacc[0] (rows equal by ones-A)
  {
    const float inv = 1.0f / laccB[0];
#pragma unroll
    for (int dblk = 0; dblk < 4; dblk++) {
      hv4 o;
#pragma unroll
      for (int j = 0; j < 4; j++) o[j] = (_Float16)(oaccB[dblk][j] * inv);
      *reinterpret_cast<hv4*>(Op + (size_t)qgB * 1024 + dblk * 16 + g * 4) = o;
    }
  }
  {
    const float inv = 1.0f / laccA[0];
#pragma unroll
    for (int dblk = 0; dblk < 4; dblk++) {
      hv4 o;
#pragma unroll
      for (int j = 0; j < 4; j++) o[j] = (_Float16)(oaccA[dblk][j] * inv);
      *reinterpret_cast<hv4*>(Op + (size_t)qgA * 1024 + dblk * 16 + g * 4) = o;
    }
  }
}

extern "C" void kernel_launch(void* const* d_in, const int* in_sizes, int n_in,
                              void* d_out, int out_size, void* d_ws, size_t ws_size,
                              hipStream_t stream) {
  const float* x = (const float*)d_in[0];
  const float* wq = (const float*)d_in[1];
  const float* wk = (const float*)d_in[2];
  const float* wv = (const float*)d_in[3];
  const float* wo = (const float*)d_in[4];
  float* out = (float*)d_out;
  char* ws = (char*)d_ws;
  const size_t MB = 1ull << 20;
  _Float16* xb   = (_Float16*)(ws + 0 * MB);   // 8 MB (A operand for QKV gemm)
  _Float16* wqkv = (_Float16*)(ws + 8 * MB);   // 6 MB (wq|wk|wv contiguous rows)
  _Float16* wob  = (_Float16*)(ws + 14 * MB);  // 2 MB
  _Float16* QKV  = (_Float16*)(ws + 16 * MB);  // 24 MB [4096][3072]
  _Float16* Vtb  = (_Float16*)(ws + 40 * MB);  // 8 MB  [32][64][2048] pi-permuted
  _Float16* Ab   = (_Float16*)(ws + 0 * MB);   // 8 MB  (reuses xb after QKV gemm)

  cvt_kernel<<<2048, 256, 0, stream>>>(x, xb, 4194304);
  cvt_w_kernel<<<4096, 256, 0, stream>>>(wq, wk, wv, wo, wqkv, wob);

  // fused Q|K|V projection: [4096][3072]
  gemm_nt<128, _Float16><<<dim3(24, 32), 256, 0, stream>>>(xb, wqkv, QKV, 4096, 3072, 1024);

  rope_kernel<<<16384, 256, 0, stream>>>(QKV);
  vtrans_kernel<<<dim3(32, 32), 256, 0, stream>>>(QKV, Vtb);

  attn_kernel<<<dim3(16, 32), 256, 0, stream>>>(QKV, Vtb, Ab);

  gemm_nt<64, float><<<dim3(8, 64), 256, 0, stream>>>(Ab, wob, out, 4096, 1024, 1024);
}

// Round 11
// 129.326 us; speedup vs baseline: 1.4282x; 1.0192x over previous
//
#include <hip/hip_runtime.h>
#include <math.h>

typedef _Float16 hv8 __attribute__((ext_vector_type(8)));
typedef _Float16 hv4 __attribute__((ext_vector_type(4)));
typedef _Float16 hv2 __attribute__((ext_vector_type(2)));
typedef float f32x4 __attribute__((ext_vector_type(4)));

#define LDS_AS(p) ((__attribute__((address_space(3))) void*)(p))
#define GLB_AS(p) ((const __attribute__((address_space(1))) void*)(p))

// single-instruction base-2 exp (bypasses OCML; v_exp_f32 is the native trans op)
__device__ __forceinline__ float fexp2(float x) {
  float r;
  asm("v_exp_f32 %0, %1" : "=v"(r) : "v"(x));
  return r;
}

// ---------------- fp32 -> fp16 convert: x (4M) + wq|wk|wv -> wqkv + wo -> wob, one launch ----
__global__ void cvt_all_kernel(const float* __restrict__ x, const float* __restrict__ wq,
                               const float* __restrict__ wk, const float* __restrict__ wv,
                               const float* __restrict__ wo, _Float16* __restrict__ xb,
                               _Float16* __restrict__ wqkv, _Float16* __restrict__ wob) {
  const int i = (blockIdx.x * blockDim.x + threadIdx.x) * 4;  // 0 .. 8M-4
  const float* s;
  _Float16* d;
  int r;
  if (i < 4194304) {                      // x segment (block-uniform: 1M boundaries)
    s = x; d = xb; r = i;
  } else {
    const int j = i - 4194304;
    const int seg = j >> 20;
    r = j & 1048575;
    s = (seg == 0) ? wq : (seg == 1) ? wk : (seg == 2) ? wv : wo;
    d = (seg < 3) ? (wqkv + (size_t)seg * 1048576) : wob;
  }
  const float4 v = *reinterpret_cast<const float4*>(s + r);
  hv4 o = {(_Float16)v.x, (_Float16)v.y, (_Float16)v.z, (_Float16)v.w};
  *reinterpret_cast<hv4*>(d + r) = o;
}

// ---------------- RoPE cos/sin table: tab[pos*32+i] = (cos, sin) of pos*freq_i ----------------
__global__ void rope_tab_kernel(float2* __restrict__ tab) {
  const int idx = blockIdx.x * blockDim.x + threadIdx.x;  // 65536
  const int pos = idx >> 5, i = idx & 31;
  const float freq = exp2f((float)i * (-13.287712379549449f / 32.0f));
  float s, c;
  sincosf((float)pos * freq, &s, &c);
  tab[idx] = make_float2(c, s);
}

// ---------------- RoPE in-place on fused QKV [4096][3072], table-driven, hv8 ----------------
__global__ void rope_kernel(_Float16* __restrict__ T, const float2* __restrict__ tab) {
  const int idx = blockIdx.x * blockDim.x + threadIdx.x;  // 2M threads
  const int row = idx >> 8;          // 0..4095
  const int c8 = (idx & 255) * 8;    // col in Q|K region, 8-elem chunk (4 rope pairs)
  const int pos = row & 2047;
  const int i0 = (c8 & 63) >> 1;     // pair index of first pair (multiple of 4)
  const size_t off = (size_t)row * 3072 + c8;
  hv8 v = *reinterpret_cast<const hv8*>(T + off);
  const float2* tp = tab + pos * 32 + i0;
  const float4 t01 = *reinterpret_cast<const float4*>(tp);      // c0,s0,c1,s1
  const float4 t23 = *reinterpret_cast<const float4*>(tp + 2);  // c2,s2,c3,s3
  const float c[4] = {t01.x, t01.z, t23.x, t23.z};
  const float s[4] = {t01.y, t01.w, t23.y, t23.w};
#pragma unroll
  for (int k = 0; k < 4; k++) {
    const float e = (float)v[2 * k], o = (float)v[2 * k + 1];
    v[2 * k] = (_Float16)(e * c[k] - o * s[k]);
    v[2 * k + 1] = (_Float16)(e * s[k] + o * c[k]);
  }
  *reinterpret_cast<hv8*>(T + off) = v;
}

// ---------------- V transpose with pi-permuted kv storage ---------------- (unchanged)
__global__ __launch_bounds__(256) void vtrans_kernel(const _Float16* __restrict__ QKV,
                                                     _Float16* __restrict__ Vt) {
  __shared__ __align__(16) _Float16 Ts[64][72];
  const int t = threadIdx.x;
  const int n0 = blockIdx.x * 64;
  const int bh = blockIdx.y;
  const int b = bh >> 4, h = bh & 15;
  const _Float16* src = QKV + (size_t)(b * 2048 + n0) * 3072 + 2048 + h * 64;
#pragma unroll
  for (int i = 0; i < 2; i++) {
    const int s = i * 256 + t, r = s >> 3, c = (s & 7) * 8;
    *reinterpret_cast<hv8*>(&Ts[r][c]) = *reinterpret_cast<const hv8*>(src + (size_t)r * 3072 + c);
  }
  __syncthreads();
  _Float16* dst = Vt + (size_t)bh * 64 * 2048 + n0;
#pragma unroll
  for (int i = 0; i < 2; i++) {
    const int s = i * 256 + t, c = s >> 3, r0 = (s & 7) * 8;  // kv rows r0..r0+7, col d=c
    const int base0 = (r0 & 32) + ((r0 & 8) ? 16 : 0) + ((r0 & 16) ? 4 : 0);
    hv4 o0, o1;
#pragma unroll
    for (int k = 0; k < 4; k++) { o0[k] = Ts[r0 + k][c]; o1[k] = Ts[r0 + 4 + k][c]; }
    *reinterpret_cast<hv4*>(dst + (size_t)c * 2048 + base0) = o0;
    *reinterpret_cast<hv4*>(dst + (size_t)c * 2048 + base0 + 8) = o1;
  }
}

// ---------------- NT GEMM: C[m][n] = sum_k A[m][k] * B[n][k] ----------------
// BM x 128 tile, BK=64 (32 MFMA per barrier-pair), 4 waves (2x2), XOR-swizzled LDS
// (pre-swizzled global source + XOR'd fragment reads; same pattern as attn, 0 conflicts).
template <int BM, typename OutT>
__global__ __launch_bounds__(256) void gemm_nt(const _Float16* __restrict__ A,
                                               const _Float16* __restrict__ B,
                                               OutT* __restrict__ C,
                                               const int M, const int N, const int K) {
  constexpr int MI = BM / 32;      // m-frags per wave
  constexpr int ALOADS = BM / 32;  // gload_lds issues per thread for A (BM*64/(256*8))
  __shared__ __align__(16) _Float16 As[BM * 64];
  __shared__ __align__(16) _Float16 Bs[128 * 64];
  const int t = threadIdx.x;
  const int w = t >> 6, lane = t & 63;
  const int wr = w >> 1, wc = w & 1;
  const int g = lane >> 4, lr = lane & 15;
  const int mBase = blockIdx.y * BM, nBase = blockIdx.x * 128;

  f32x4 acc[MI][4];
#pragma unroll
  for (int a = 0; a < MI; a++)
#pragma unroll
    for (int bb = 0; bb < 4; bb++) acc[a][bb] = {0.f, 0.f, 0.f, 0.f};

  for (int k0 = 0; k0 < K; k0 += 64) {
    // stage A [BM][64] and B [128][64], XOR-swizzled source (LDS[r][c] = G[r][c ^ (r&7)])
#pragma unroll
    for (int i = 0; i < ALOADS; i++) {
      const int s = i * 256 + t;
      const int r = s >> 3;
      const int cs = ((s & 7) ^ (r & 7)) * 8;
      __builtin_amdgcn_global_load_lds(GLB_AS(A + (size_t)(mBase + r) * K + k0 + cs),
                                       LDS_AS(As + s * 8), 16, 0, 0);
    }
#pragma unroll
    for (int i = 0; i < 4; i++) {
      const int s = i * 256 + t;
      const int r = s >> 3;
      const int cs = ((s & 7) ^ (r & 7)) * 8;
      __builtin_amdgcn_global_load_lds(GLB_AS(B + (size_t)(nBase + r) * K + k0 + cs),
                                       LDS_AS(Bs + s * 8), 16, 0, 0);
    }
    __syncthreads();
#pragma unroll
    for (int ks = 0; ks < 2; ks++) {
      hv8 af[MI], bfr[4];
#pragma unroll
      for (int mi = 0; mi < MI; mi++) {
        const int ra = wr * (BM / 2) + mi * 16 + lr;
        af[mi] = *reinterpret_cast<const hv8*>(As + ra * 64 + (((ks * 4 + g) ^ (ra & 7)) * 8));
      }
#pragma unroll
      for (int ni = 0; ni < 4; ni++) {
        const int rb = wc * 64 + ni * 16 + lr;
        bfr[ni] = *reinterpret_cast<const hv8*>(Bs + rb * 64 + (((ks * 4 + g) ^ (rb & 7)) * 8));
      }
#pragma unroll
      for (int mi = 0; mi < MI; mi++)
#pragma unroll
        for (int ni = 0; ni < 4; ni++)
          acc[mi][ni] = __builtin_amdgcn_mfma_f32_16x16x32_f16(af[mi], bfr[ni], acc[mi][ni], 0, 0, 0);
    }
    __syncthreads();
  }
  // epilogue: C/D layout col=lane&15, row=(lane>>4)*4+j
#pragma unroll
  for (int mi = 0; mi < MI; mi++) {
#pragma unroll
    for (int j = 0; j < 4; j++) {
      const size_t row = mBase + wr * (BM / 2) + mi * 16 + g * 4 + j;
#pragma unroll
      for (int ni = 0; ni < 4; ni++) {
        const int col = nBase + wc * 64 + ni * 16 + lr;
        C[row * N + col] = (OutT)acc[mi][ni][j];
      }
    }
  }
}

// ---------------- flash causal attention ---------------- (unchanged from R10)
__global__ __launch_bounds__(256, 2) void attn_kernel(const _Float16* __restrict__ QKV,
                                                      const _Float16* __restrict__ Vt,
                                                      _Float16* __restrict__ O) {
  __shared__ __align__(16) _Float16 Ks[2][64 * 64];
  __shared__ __align__(16) _Float16 Vs[2][64 * 64];
  const int t = threadIdx.x;
  const int w = t >> 6, lane = t & 63;
  const int g = lane >> 4, lr = lane & 15;
  const int qtA = blockIdx.x;        // 0..15  (light q-tile)
  const int qtB = 31 - qtA;          // 16..31 (heavy q-tile)
  const int m0A = qtA * 64, m0B = qtB * 64;
  const int bh = blockIdx.y;
  const int b = bh >> 4, h = bh & 15;
  const _Float16* Qp = QKV + (size_t)b * 2048 * 3072 + h * 64;
  const _Float16* Kp = Qp + 1024;
  const _Float16* Vp = Vt + (size_t)bh * 64 * 2048;
  _Float16* Op = O + (size_t)b * 2048 * 1024 + h * 64;

  const int qgA = m0A + w * 16 + lr;
  const int qgB = m0B + w * 16 + lr;

  hv8 qfA[2], qfB[2];
#pragma unroll
  for (int ks = 0; ks < 2; ks++) {
    qfA[ks] = *reinterpret_cast<const hv8*>(Qp + (size_t)qgA * 3072 + ks * 32 + g * 8);
    qfA[ks] = qfA[ks] * (_Float16)0.18033688f;
    qfB[ks] = *reinterpret_cast<const hv8*>(Qp + (size_t)qgB * 3072 + ks * 32 + g * 8);
    qfB[ks] = qfB[ks] * (_Float16)0.18033688f;
  }

  const hv8 onesf = {(_Float16)1.0f, (_Float16)1.0f, (_Float16)1.0f, (_Float16)1.0f,
                     (_Float16)1.0f, (_Float16)1.0f, (_Float16)1.0f, (_Float16)1.0f};

  auto STAGE = [&](int kv0, int bi) {
#pragma unroll
    for (int i = 0; i < 2; i++) {
      const int s = i * 256 + t;
      const int r = s >> 3;
      const int cs = ((s & 7) ^ (r & 7)) * 8;
      __builtin_amdgcn_global_load_lds(GLB_AS(Kp + (size_t)(kv0 + r) * 3072 + cs),
                                       LDS_AS(&Ks[bi][s * 8]), 16, 0, 0);
      __builtin_amdgcn_global_load_lds(GLB_AS(Vp + (size_t)r * 2048 + kv0 + cs),
                                       LDS_AS(&Vs[bi][s * 8]), 16, 0, 0);
    }
  };

  f32x4 oaccA[4], oaccB[4];
#pragma unroll
  for (int d = 0; d < 4; d++) { oaccA[d] = {0.f, 0.f, 0.f, 0.f}; oaccB[d] = {0.f, 0.f, 0.f, 0.f}; }
  f32x4 laccA = {0.f, 0.f, 0.f, 0.f}, laccB = {0.f, 0.f, 0.f, 0.f};
  float mstA = -INFINITY, mstB = -INFINITY;

  auto HALF = [&](const _Float16* Kb, const _Float16* Vb, const hv8* qf, bool diag,
                  int qg_, int kv0, float& mst, f32x4* oacc, f32x4& lacc) {
    f32x4 sf[4];
#pragma unroll
    for (int nf = 0; nf < 4; nf++) sf[nf] = {0.f, 0.f, 0.f, 0.f};
#pragma unroll
    for (int ks = 0; ks < 2; ks++)
#pragma unroll
      for (int nf = 0; nf < 4; nf++) {
        const hv8 kf = *reinterpret_cast<const hv8*>(
            Kb + (nf * 16 + lr) * 64 + (((ks * 4 + g) ^ (lr & 7)) * 8));
        sf[nf] = __builtin_amdgcn_mfma_f32_16x16x32_f16(kf, qf[ks], sf[nf], 0, 0, 0);
      }
    float p[4][4];
#pragma unroll
    for (int nf = 0; nf < 4; nf++)
#pragma unroll
      for (int j = 0; j < 4; j++) {
        float x = sf[nf][j];
        if (diag && (kv0 + nf * 16 + g * 4 + j > qg_)) x = -INFINITY;
        p[nf][j] = x;
      }
    float r4[4];
#pragma unroll
    for (int nf = 0; nf < 4; nf++)
      r4[nf] = fmaxf(fmaxf(p[nf][0], p[nf][1]), fmaxf(p[nf][2], p[nf][3]));
    const float rm = fmaxf(fmaxf(r4[0], r4[1]), fmaxf(r4[2], r4[3]));
    if (!__all(rm <= mst + 8.0f)) {
      float rw = fmaxf(rm, __shfl_xor(rm, 16));
      rw = fmaxf(rw, __shfl_xor(rw, 32));
      const float mn = fmaxf(mst, rw);
      const float corr = fexp2(mst - mn);  // first tile: exp2(-inf)=0
#pragma unroll
      for (int d = 0; d < 4; d++) oacc[d] *= corr;
      lacc *= corr;
      mst = mn;
    }
#pragma unroll
    for (int nf = 0; nf < 4; nf++)
#pragma unroll
      for (int j = 0; j < 4; j++) p[nf][j] = fexp2(p[nf][j] - mst);
    hv8 pf[2];
#pragma unroll
    for (int ks = 0; ks < 2; ks++) {
      const auto c0 = __builtin_amdgcn_cvt_pkrtz(p[2 * ks][0], p[2 * ks][1]);
      const auto c1 = __builtin_amdgcn_cvt_pkrtz(p[2 * ks][2], p[2 * ks][3]);
      const auto c2 = __builtin_amdgcn_cvt_pkrtz(p[2 * ks + 1][0], p[2 * ks + 1][1]);
      const auto c3 = __builtin_amdgcn_cvt_pkrtz(p[2 * ks + 1][2], p[2 * ks + 1][3]);
      pf[ks][0] = (_Float16)c0[0]; pf[ks][1] = (_Float16)c0[1];
      pf[ks][2] = (_Float16)c1[0]; pf[ks][3] = (_Float16)c1[1];
      pf[ks][4] = (_Float16)c2[0]; pf[ks][5] = (_Float16)c2[1];
      pf[ks][6] = (_Float16)c3[0]; pf[ks][7] = (_Float16)c3[1];
    }
#pragma unroll
    for (int dblk = 0; dblk < 4; dblk++) {
      const int row = dblk * 16 + lr;
#pragma unroll
      for (int ks = 0; ks < 2; ks++) {
        const hv8 vtf = *reinterpret_cast<const hv8*>(
            Vb + row * 64 + (((ks * 4 + g) ^ (row & 7)) * 8));
        oacc[dblk] = __builtin_amdgcn_mfma_f32_16x16x32_f16(vtf, pf[ks], oacc[dblk], 0, 0, 0);
      }
    }
#pragma unroll
    for (int ks = 0; ks < 2; ks++)
      lacc = __builtin_amdgcn_mfma_f32_16x16x32_f16(onesf, pf[ks], lacc, 0, 0, 0);
  };

  const int ntB = qtB + 1;
  STAGE(0, 0);
  int cur = 0;

  for (int tt = 0; tt < ntB; tt++) {
    __syncthreads();  // implicit vmcnt(0): tile tt staged; buffer cur^1 free
    if (tt + 1 < ntB) STAGE((tt + 1) * 64, cur ^ 1);
    const int kv0 = tt * 64;
    const _Float16* Kb = Ks[cur];
    const _Float16* Vb = Vs[cur];

    HALF(Kb, Vb, qfB, tt == qtB, qgB, kv0, mstB, oaccB, laccB);
    if (tt <= qtA) HALF(Kb, Vb, qfA, tt == qtA, qgA, kv0, mstA, oaccA, laccA);
    cur ^= 1;
  }

  {
    const float inv = 1.0f / laccB[0];
#pragma unroll
    for (int dblk = 0; dblk < 4; dblk++) {
      hv4 o;
#pragma unroll
      for (int j = 0; j < 4; j++) o[j] = (_Float16)(oaccB[dblk][j] * inv);
      *reinterpret_cast<hv4*>(Op + (size_t)qgB * 1024 + dblk * 16 + g * 4) = o;
    }
  }
  {
    const float inv = 1.0f / laccA[0];
#pragma unroll
    for (int dblk = 0; dblk < 4; dblk++) {
      hv4 o;
#pragma unroll
      for (int j = 0; j < 4; j++) o[j] = (_Float16)(oaccA[dblk][j] * inv);
      *reinterpret_cast<hv4*>(Op + (size_t)qgA * 1024 + dblk * 16 + g * 4) = o;
    }
  }
}

extern "C" void kernel_launch(void* const* d_in, const int* in_sizes, int n_in,
                              void* d_out, int out_size, void* d_ws, size_t ws_size,
                              hipStream_t stream) {
  const float* x = (const float*)d_in[0];
  const float* wq = (const float*)d_in[1];
  const float* wk = (const float*)d_in[2];
  const float* wv = (const float*)d_in[3];
  const float* wo = (const float*)d_in[4];
  float* out = (float*)d_out;
  char* ws = (char*)d_ws;
  const size_t MB = 1ull << 20;
  _Float16* xb   = (_Float16*)(ws + 0 * MB);   // 8 MB (A operand for QKV gemm)
  _Float16* wqkv = (_Float16*)(ws + 8 * MB);   // 6 MB (wq|wk|wv contiguous rows)
  _Float16* wob  = (_Float16*)(ws + 14 * MB);  // 2 MB
  _Float16* QKV  = (_Float16*)(ws + 16 * MB);  // 24 MB [4096][3072]
  _Float16* Vtb  = (_Float16*)(ws + 40 * MB);  // 8 MB  [32][64][2048] pi-permuted
  float2*   rtab = (float2*)(ws + 48 * MB);    // 512 KB cos/sin table
  _Float16* Ab   = (_Float16*)(ws + 0 * MB);   // 8 MB  (reuses xb after QKV gemm)

  rope_tab_kernel<<<256, 256, 0, stream>>>(rtab);
  cvt_all_kernel<<<8192, 256, 0, stream>>>(x, wq, wk, wv, wo, xb, wqkv, wob);

  // fused Q|K|V projection: [4096][3072]
  gemm_nt<128, _Float16><<<dim3(24, 32), 256, 0, stream>>>(xb, wqkv, QKV, 4096, 3072, 1024);

  rope_kernel<<<8192, 256, 0, stream>>>(QKV, rtab);
  vtrans_kernel<<<dim3(32, 32), 256, 0, stream>>>(QKV, Vtb);

  attn_kernel<<<dim3(16, 32), 256, 0, stream>>>(QKV, Vtb, Ab);

  gemm_nt<64, float><<<dim3(8, 64), 256, 0, stream>>>(Ab, wob, out, 4096, 1024, 1024);
}

// Round 13
// 113.070 us; speedup vs baseline: 1.6336x; 1.1438x over previous
//
#include <hip/hip_runtime.h>
#include <math.h>

typedef _Float16 hv8 __attribute__((ext_vector_type(8)));
typedef _Float16 hv4 __attribute__((ext_vector_type(4)));
typedef _Float16 hv2 __attribute__((ext_vector_type(2)));
typedef float f32x4 __attribute__((ext_vector_type(4)));

#define LDS_AS(p) ((__attribute__((address_space(3))) void*)(p))
#define GLB_AS(p) ((const __attribute__((address_space(1))) void*)(p))

// single-instruction base-2 exp (bypasses OCML; v_exp_f32 is the native trans op)
__device__ __forceinline__ float fexp2(float x) {
  float r;
  asm("v_exp_f32 %0, %1" : "=v"(r) : "v"(x));
  return r;
}

// ---------------- prep: rope cos/sin table + fp32->fp16 converts, one launch ----------------
// blocks 0..255: rope table (65536 entries). blocks 256..8447: cvt x|wq|wk|wv|wo.
__global__ void prep_kernel(const float* __restrict__ x, const float* __restrict__ wq,
                            const float* __restrict__ wk, const float* __restrict__ wv,
                            const float* __restrict__ wo, _Float16* __restrict__ xb,
                            _Float16* __restrict__ wqkv, _Float16* __restrict__ wob,
                            float2* __restrict__ tab) {
  const int bid = blockIdx.x;
  if (bid < 256) {
    const int idx = bid * 256 + threadIdx.x;  // 65536
    const int pos = idx >> 5, i = idx & 31;
    const float freq = exp2f((float)i * (-13.287712379549449f / 32.0f));
    float s, c;
    sincosf((float)pos * freq, &s, &c);
    tab[idx] = make_float2(c, s);
    return;
  }
  const int i = ((bid - 256) * 256 + threadIdx.x) * 4;  // 0 .. 8M-4
  const float* s;
  _Float16* d;
  int r;
  if (i < 4194304) {  // x segment (block-uniform: 1M boundaries)
    s = x; d = xb; r = i;
  } else {
    const int j = i - 4194304;
    const int seg = j >> 20;
    r = j & 1048575;
    s = (seg == 0) ? wq : (seg == 1) ? wk : (seg == 2) ? wv : wo;
    d = (seg < 3) ? (wqkv + (size_t)seg * 1048576) : wob;
  }
  const float4 v = *reinterpret_cast<const float4*>(s + r);
  hv4 o = {(_Float16)v.x, (_Float16)v.y, (_Float16)v.z, (_Float16)v.w};
  *reinterpret_cast<hv4*>(d + r) = o;
}

// ---------------- rope (table-driven, hv8) + V transpose, one launch ----------------
// blocks 0..4095: RoPE in-place on QKV rows 0..4095 cols 0..2047 (exactly 1M threads x 8
// elems = 8M = the whole Q|K region; R10-R12 launched 2x this -> OOB rows 4096..8191
// clobbered Vtb/rtab, exposed by R12's fusion). blocks 4096..5119: vtrans.
__global__ __launch_bounds__(256) void ropevt_kernel(_Float16* __restrict__ QKV,
                                                     const float2* __restrict__ tab,
                                                     _Float16* __restrict__ Vt) {
  __shared__ __align__(16) _Float16 Ts[64][72];
  const int bid = blockIdx.x;
  if (bid < 4096) {
    const int idx = bid * 256 + threadIdx.x;  // 1M threads
    const int row = idx >> 8;          // 0..4095
    const int c8 = (idx & 255) * 8;    // col in Q|K region (4 rope pairs)
    const int pos = row & 2047;
    const int i0 = (c8 & 63) >> 1;
    const size_t off = (size_t)row * 3072 + c8;
    hv8 v = *reinterpret_cast<const hv8*>(QKV + off);
    const float2* tp = tab + pos * 32 + i0;
    const float4 t01 = *reinterpret_cast<const float4*>(tp);
    const float4 t23 = *reinterpret_cast<const float4*>(tp + 2);
    const float c[4] = {t01.x, t01.z, t23.x, t23.z};
    const float s[4] = {t01.y, t01.w, t23.y, t23.w};
#pragma unroll
    for (int k = 0; k < 4; k++) {
      const float e = (float)v[2 * k], o = (float)v[2 * k + 1];
      v[2 * k] = (_Float16)(e * c[k] - o * s[k]);
      v[2 * k + 1] = (_Float16)(e * s[k] + o * c[k]);
    }
    *reinterpret_cast<hv8*>(QKV + off) = v;
    return;
  }
  // V transpose with pi-permuted kv storage (verified 0-conflict PV reads)
  const int t = threadIdx.x;
  const int vb = bid - 4096;
  const int n0 = (vb & 31) * 64;
  const int bh = vb >> 5;
  const int b = bh >> 4, h = bh & 15;
  const _Float16* src = QKV + (size_t)(b * 2048 + n0) * 3072 + 2048 + h * 64;
#pragma unroll
  for (int i = 0; i < 2; i++) {
    const int s = i * 256 + t, r = s >> 3, c = (s & 7) * 8;
    *reinterpret_cast<hv8*>(&Ts[r][c]) = *reinterpret_cast<const hv8*>(src + (size_t)r * 3072 + c);
  }
  __syncthreads();
  _Float16* dst = Vt + (size_t)bh * 64 * 2048 + n0;
#pragma unroll
  for (int i = 0; i < 2; i++) {
    const int s = i * 256 + t, c = s >> 3, r0 = (s & 7) * 8;  // kv rows r0..r0+7, col d=c
    const int base0 = (r0 & 32) + ((r0 & 8) ? 16 : 0) + ((r0 & 16) ? 4 : 0);
    hv4 o0, o1;
#pragma unroll
    for (int k = 0; k < 4; k++) { o0[k] = Ts[r0 + k][c]; o1[k] = Ts[r0 + 4 + k][c]; }
    *reinterpret_cast<hv4*>(dst + (size_t)c * 2048 + base0) = o0;
    *reinterpret_cast<hv4*>(dst + (size_t)c * 2048 + base0 + 8) = o1;
  }
}

// ---------------- NT GEMM: C[m][n] = sum_k A[m][k] * B[n][k] ---------------- (R11, unchanged)
// BM x 128 tile, BK=64 (32 MFMA per barrier-pair), 4 waves (2x2), XOR-swizzled LDS.
template <int BM, typename OutT>
__global__ __launch_bounds__(256) void gemm_nt(const _Float16* __restrict__ A,
                                               const _Float16* __restrict__ B,
                                               OutT* __restrict__ C,
                                               const int M, const int N, const int K) {
  constexpr int MI = BM / 32;
  constexpr int ALOADS = BM / 32;
  __shared__ __align__(16) _Float16 As[BM * 64];
  __shared__ __align__(16) _Float16 Bs[128 * 64];
  const int t = threadIdx.x;
  const int w = t >> 6, lane = t & 63;
  const int wr = w >> 1, wc = w & 1;
  const int g = lane >> 4, lr = lane & 15;
  const int mBase = blockIdx.y * BM, nBase = blockIdx.x * 128;

  f32x4 acc[MI][4];
#pragma unroll
  for (int a = 0; a < MI; a++)
#pragma unroll
    for (int bb = 0; bb < 4; bb++) acc[a][bb] = {0.f, 0.f, 0.f, 0.f};

  for (int k0 = 0; k0 < K; k0 += 64) {
#pragma unroll
    for (int i = 0; i < ALOADS; i++) {
      const int s = i * 256 + t;
      const int r = s >> 3;
      const int cs = ((s & 7) ^ (r & 7)) * 8;
      __builtin_amdgcn_global_load_lds(GLB_AS(A + (size_t)(mBase + r) * K + k0 + cs),
                                       LDS_AS(As + s * 8), 16, 0, 0);
    }
#pragma unroll
    for (int i = 0; i < 4; i++) {
      const int s = i * 256 + t;
      const int r = s >> 3;
      const int cs = ((s & 7) ^ (r & 7)) * 8;
      __builtin_amdgcn_global_load_lds(GLB_AS(B + (size_t)(nBase + r) * K + k0 + cs),
                                       LDS_AS(Bs + s * 8), 16, 0, 0);
    }
    __syncthreads();
#pragma unroll
    for (int ks = 0; ks < 2; ks++) {
      hv8 af[MI], bfr[4];
#pragma unroll
      for (int mi = 0; mi < MI; mi++) {
        const int ra = wr * (BM / 2) + mi * 16 + lr;
        af[mi] = *reinterpret_cast<const hv8*>(As + ra * 64 + (((ks * 4 + g) ^ (ra & 7)) * 8));
      }
#pragma unroll
      for (int ni = 0; ni < 4; ni++) {
        const int rb = wc * 64 + ni * 16 + lr;
        bfr[ni] = *reinterpret_cast<const hv8*>(Bs + rb * 64 + (((ks * 4 + g) ^ (rb & 7)) * 8));
      }
#pragma unroll
      for (int mi = 0; mi < MI; mi++)
#pragma unroll
        for (int ni = 0; ni < 4; ni++)
          acc[mi][ni] = __builtin_amdgcn_mfma_f32_16x16x32_f16(af[mi], bfr[ni], acc[mi][ni], 0, 0, 0);
    }
    __syncthreads();
  }
#pragma unroll
  for (int mi = 0; mi < MI; mi++) {
#pragma unroll
    for (int j = 0; j < 4; j++) {
      const size_t row = mBase + wr * (BM / 2) + mi * 16 + g * 4 + j;
#pragma unroll
      for (int ni = 0; ni < 4; ni++) {
        const int col = nBase + wc * 64 + ni * 16 + lr;
        C[row * N + col] = (OutT)acc[mi][ni][j];
      }
    }
  }
}

// ---------------- flash causal attention, 4 blocks/CU, CU-balanced qt mapping ----------------
// One 64-row q-tile per 4-wave block; grid 1024 (= 4 blocks/CU = 4 waves/SIMD). CU-level
// balance: co-resident blocks (ids congruent mod 256) get q-tiles {base, 31-base, base+8,
// 23-base} summing to 66 tile-units for every base. Double-buffered staging, swapped QK^T,
// in-register exp2 softmax (ballot-gated defer-max, v_exp_f32, ones-MFMA row-sum),
// pi-permuted Vt -> b128 PV A-frags (0 bank conflicts).
__global__ __launch_bounds__(256, 4) void attn_kernel(const _Float16* __restrict__ QKV,
                                                      const _Float16* __restrict__ Vt,
                                                      _Float16* __restrict__ O) {
  __shared__ __align__(16) _Float16 Ks[2][64 * 64];
  __shared__ __align__(16) _Float16 Vs[2][64 * 64];
  const int t = threadIdx.x;
  const int w = t >> 6, lane = t & 63;
  const int g = lane >> 4, lr = lane & 15;
  // CU-balanced q-tile mapping
  const int id = blockIdx.x;
  const int j = id >> 8, r = id & 255;
  const int bh = r & 31, base = r >> 5;
  const int half = j >> 1;
  const int qt = (j & 1) ? (31 - base - 8 * half) : (base + 8 * half);
  const int m0 = qt * 64;
  const int b = bh >> 4, h = bh & 15;
  const _Float16* Qp = QKV + (size_t)b * 2048 * 3072 + h * 64;
  const _Float16* Kp = Qp + 1024;
  const _Float16* Vp = Vt + (size_t)bh * 64 * 2048;
  _Float16* Op = O + (size_t)b * 2048 * 1024 + h * 64;

  const int qg = m0 + w * 16 + lr;  // this lane's q row

  // Q B-frag (n=q, k=g*8+i), pre-scaled by (1/8)*log2(e) for exp2-domain softmax
  hv8 qf[2];
#pragma unroll
  for (int ks = 0; ks < 2; ks++) {
    qf[ks] = *reinterpret_cast<const hv8*>(Qp + (size_t)qg * 3072 + ks * 32 + g * 8);
    qf[ks] = qf[ks] * (_Float16)0.18033688f;
  }

  const hv8 onesf = {(_Float16)1.0f, (_Float16)1.0f, (_Float16)1.0f, (_Float16)1.0f,
                     (_Float16)1.0f, (_Float16)1.0f, (_Float16)1.0f, (_Float16)1.0f};

  auto STAGE = [&](int kv0, int bi) {
#pragma unroll
    for (int i = 0; i < 2; i++) {
      const int s = i * 256 + t;
      const int rr = s >> 3;
      const int cs = ((s & 7) ^ (rr & 7)) * 8;
      __builtin_amdgcn_global_load_lds(GLB_AS(Kp + (size_t)(kv0 + rr) * 3072 + cs),
                                       LDS_AS(&Ks[bi][s * 8]), 16, 0, 0);
      __builtin_amdgcn_global_load_lds(GLB_AS(Vp + (size_t)rr * 2048 + kv0 + cs),
                                       LDS_AS(&Vs[bi][s * 8]), 16, 0, 0);
    }
  };

  f32x4 oacc[4];
#pragma unroll
  for (int d = 0; d < 4; d++) oacc[d] = {0.f, 0.f, 0.f, 0.f};
  f32x4 lacc = {0.f, 0.f, 0.f, 0.f};
  float mst = -INFINITY;

  const int nt = qt + 1;
  STAGE(0, 0);
  int cur = 0;

  for (int tt = 0; tt < nt; tt++) {
    __syncthreads();  // implicit vmcnt(0): tile tt staged; buffer cur^1 free
    if (tt + 1 < nt) STAGE((tt + 1) * 64, cur ^ 1);
    const int kv0 = tt * 64;
    const _Float16* Kb = Ks[cur];
    const _Float16* Vb = Vs[cur];

    // S^T = K Q^T : A = K rows (m=kv), B = Q (n=q). 4 kv-frags x 2 k-steps.
    f32x4 sf[4];
#pragma unroll
    for (int nf = 0; nf < 4; nf++) sf[nf] = {0.f, 0.f, 0.f, 0.f};
#pragma unroll
    for (int ks = 0; ks < 2; ks++)
#pragma unroll
      for (int nf = 0; nf < 4; nf++) {
        const hv8 kf = *reinterpret_cast<const hv8*>(
            Kb + (nf * 16 + lr) * 64 + (((ks * 4 + g) ^ (lr & 7)) * 8));
        sf[nf] = __builtin_amdgcn_mfma_f32_16x16x32_f16(kf, qf[ks], sf[nf], 0, 0, 0);
      }

    // softmax (base-2, in-register, shfl-free steady state)
    const bool diag = (tt == nt - 1);
    float p[4][4];
#pragma unroll
    for (int nf = 0; nf < 4; nf++)
#pragma unroll
      for (int jj = 0; jj < 4; jj++) {
        float xv = sf[nf][jj];
        if (diag && (kv0 + nf * 16 + g * 4 + jj > qg)) xv = -INFINITY;
        p[nf][jj] = xv;
      }
    float r4[4];
#pragma unroll
    for (int nf = 0; nf < 4; nf++)
      r4[nf] = fmaxf(fmaxf(p[nf][0], p[nf][1]), fmaxf(p[nf][2], p[nf][3]));
    const float rm = fmaxf(fmaxf(r4[0], r4[1]), fmaxf(r4[2], r4[3]));
    if (!__all(rm <= mst + 8.0f)) {
      float rw = fmaxf(rm, __shfl_xor(rm, 16));
      rw = fmaxf(rw, __shfl_xor(rw, 32));
      const float mn = fmaxf(mst, rw);
      const float corr = fexp2(mst - mn);  // first tile: exp2(-inf)=0
#pragma unroll
      for (int d = 0; d < 4; d++) oacc[d] *= corr;
      lacc *= corr;
      mst = mn;
    }
#pragma unroll
    for (int nf = 0; nf < 4; nf++)
#pragma unroll
      for (int jj = 0; jj < 4; jj++) p[nf][jj] = fexp2(p[nf][jj] - mst);

    // pf[ks][i] = P[qg][kv0 + ks*32 + (i>>2)*16 + g*4 + (i&3)]  (pi-permuted, lane-local)
    hv8 pf[2];
#pragma unroll
    for (int ks = 0; ks < 2; ks++) {
      const auto c0 = __builtin_amdgcn_cvt_pkrtz(p[2 * ks][0], p[2 * ks][1]);
      const auto c1 = __builtin_amdgcn_cvt_pkrtz(p[2 * ks][2], p[2 * ks][3]);
      const auto c2 = __builtin_amdgcn_cvt_pkrtz(p[2 * ks + 1][0], p[2 * ks + 1][1]);
      const auto c3 = __builtin_amdgcn_cvt_pkrtz(p[2 * ks + 1][2], p[2 * ks + 1][3]);
      pf[ks][0] = (_Float16)c0[0]; pf[ks][1] = (_Float16)c0[1];
      pf[ks][2] = (_Float16)c1[0]; pf[ks][3] = (_Float16)c1[1];
      pf[ks][4] = (_Float16)c2[0]; pf[ks][5] = (_Float16)c2[1];
      pf[ks][6] = (_Float16)c3[0]; pf[ks][7] = (_Float16)c3[1];
    }

    // O^T += V^T P^T (b128 swizzled A-frags); l += ones * P
#pragma unroll
    for (int dblk = 0; dblk < 4; dblk++) {
      const int row = dblk * 16 + lr;
#pragma unroll
      for (int ks = 0; ks < 2; ks++) {
        const hv8 vtf = *reinterpret_cast<const hv8*>(
            Vb + row * 64 + (((ks * 4 + g) ^ (row & 7)) * 8));
        oacc[dblk] = __builtin_amdgcn_mfma_f32_16x16x32_f16(vtf, pf[ks], oacc[dblk], 0, 0, 0);
      }
    }
#pragma unroll
    for (int ks = 0; ks < 2; ks++)
      lacc = __builtin_amdgcn_mfma_f32_16x16x32_f16(onesf, pf[ks], lacc, 0, 0, 0);
    cur ^= 1;
  }

  // epilogue: oacc[dblk][j] = O^T[d=dblk*16+g*4+j][qg]; l = lacc[0]
  const float inv = 1.0f / lacc[0];
#pragma unroll
  for (int dblk = 0; dblk < 4; dblk++) {
    hv4 o;
#pragma unroll
    for (int jj = 0; jj < 4; jj++) o[jj] = (_Float16)(oacc[dblk][jj] * inv);
    *reinterpret_cast<hv4*>(Op + (size_t)qg * 1024 + dblk * 16 + g * 4) = o;
  }
}

extern "C" void kernel_launch(void* const* d_in, const int* in_sizes, int n_in,
                              void* d_out, int out_size, void* d_ws, size_t ws_size,
                              hipStream_t stream) {
  const float* x = (const float*)d_in[0];
  const float* wq = (const float*)d_in[1];
  const float* wk = (const float*)d_in[2];
  const float* wv = (const float*)d_in[3];
  const float* wo = (const float*)d_in[4];
  float* out = (float*)d_out;
  char* ws = (char*)d_ws;
  const size_t MB = 1ull << 20;
  _Float16* xb   = (_Float16*)(ws + 0 * MB);   // 8 MB (A operand for QKV gemm)
  _Float16* wqkv = (_Float16*)(ws + 8 * MB);   // 6 MB (wq|wk|wv contiguous rows)
  _Float16* wob  = (_Float16*)(ws + 14 * MB);  // 2 MB
  _Float16* QKV  = (_Float16*)(ws + 16 * MB);  // 24 MB [4096][3072]
  _Float16* Vtb  = (_Float16*)(ws + 40 * MB);  // 8 MB  [32][64][2048] pi-permuted
  float2*   rtab = (float2*)(ws + 48 * MB);    // 512 KB cos/sin table
  _Float16* Ab   = (_Float16*)(ws + 0 * MB);   // 8 MB  (reuses xb after QKV gemm)

  prep_kernel<<<8448, 256, 0, stream>>>(x, wq, wk, wv, wo, xb, wqkv, wob, rtab);

  // fused Q|K|V projection: [4096][3072]
  gemm_nt<128, _Float16><<<dim3(24, 32), 256, 0, stream>>>(xb, wqkv, QKV, 4096, 3072, 1024);

  ropevt_kernel<<<5120, 256, 0, stream>>>(QKV, rtab, Vtb);

  attn_kernel<<<1024, 256, 0, stream>>>(QKV, Vtb, Ab);

  gemm_nt<64, float><<<dim3(8, 64), 256, 0, stream>>>(Ab, wob, out, 4096, 1024, 1024);
}